// Round 2
// baseline (2613.736 us; speedup 1.0000x reference)
//
#include <hip/hip_runtime.h>

#define S_LEN 2048
#define HIDN 4096
#define NH 32
#define DQK 192
#define DROPE 64
#define DV 128
#define QLORA 1536
#define KVLORA 512
#define LATD 576      // KVLORA + DROPE
#define HQ 6144       // NH*DQK
#define HKV 8192      // NH*(128+128)
#define HO 4096       // NH*DV

typedef float f32x4 __attribute__((ext_vector_type(4)));
typedef __bf16 bf16x8 __attribute__((ext_vector_type(8)));
typedef unsigned short u16x8 __attribute__((ext_vector_type(8)));

__device__ __forceinline__ float bf2f(unsigned short u) {
  union { unsigned int i; float f; } v; v.i = (unsigned int)u << 16; return v.f;
}
__device__ __forceinline__ unsigned short f2bf(float f) {   // RNE, finite inputs
  unsigned int u = __float_as_uint(f);
  return (unsigned short)((u + 0x7fffu + ((u >> 16) & 1u)) >> 16);
}
__device__ __forceinline__ void g2l16(const void* g, void* l) {
  __builtin_amdgcn_global_load_lds((__attribute__((address_space(1))) void*)(void*)g,
                                   (__attribute__((address_space(3))) void*)l, 16, 0, 0);
}

// ---------------- bf16 MFMA GEMM: C[M,N] = A[M,K] @ BT[N,K]^T ----------------
// m97 structure: 128x128 tile, BK=32, 256 thr (4 waves, 2x2), 4x4 16x16x32 frags/wave.
template<bool BF16_OUT>
__global__ __launch_bounds__(256) void gemm_bf16(
    const unsigned short* __restrict__ A,   // bf16 [M,K] row-major
    const unsigned short* __restrict__ BT,  // bf16 [N,K] row-major
    void* __restrict__ C, int N, int K, int lda, int ldc)
{
  __shared__ __align__(16) unsigned short As[128][32];
  __shared__ __align__(16) unsigned short Bs[128][32];
  const int t = threadIdx.x;
  const int brow = blockIdx.y, bcol = blockIdx.x;
  const int wave = t >> 6, lane = t & 63;
  const int wr = wave >> 1, wc = wave & 1;       // 64x64 per wave
  const int lm = lane & 15, lk = lane >> 4;

  f32x4 acc[4][4];
#pragma unroll
  for (int i = 0; i < 4; ++i)
#pragma unroll
    for (int j = 0; j < 4; ++j) acc[i][j] = (f32x4){0.f, 0.f, 0.f, 0.f};

  for (int k0 = 0; k0 < K; k0 += 32) {
#pragma unroll
    for (int i = 0; i < 2; ++i) {                 // A tile: 128x32 bf16 = 8KB
      const int c = t + i * 256;
      const int r = c >> 2, ko = (c & 3) * 8;
      g2l16(A + (size_t)(brow * 128 + r) * lda + k0 + ko,
            (char*)&As[0][0] + i * 4096 + wave * 1024);
    }
#pragma unroll
    for (int i = 0; i < 2; ++i) {                 // B^T tile: 128x32
      const int c = t + i * 256;
      const int r = c >> 2, ko = (c & 3) * 8;
      int n = bcol * 128 + r; if (n > N - 1) n = N - 1;   // tail clamp (junk cols unused)
      g2l16(BT + (size_t)n * K + k0 + ko,
            (char*)&Bs[0][0] + i * 4096 + wave * 1024);
    }
    __syncthreads();                              // compiler drains vmcnt before barrier
    bf16x8 af[4], bfv[4];
#pragma unroll
    for (int fm = 0; fm < 4; ++fm) af[fm] = *(const bf16x8*)&As[wr * 64 + fm * 16 + lm][lk * 8];
#pragma unroll
    for (int fn = 0; fn < 4; ++fn) bfv[fn] = *(const bf16x8*)&Bs[wc * 64 + fn * 16 + lm][lk * 8];
#pragma unroll
    for (int fm = 0; fm < 4; ++fm)
#pragma unroll
      for (int fn = 0; fn < 4; ++fn)
        acc[fm][fn] = __builtin_amdgcn_mfma_f32_16x16x32_bf16(af[fm], bfv[fn], acc[fm][fn], 0, 0, 0);
    __syncthreads();
  }

#pragma unroll
  for (int fm = 0; fm < 4; ++fm) {
    const int row = brow * 128 + wr * 64 + fm * 16 + lk * 4;
#pragma unroll
    for (int fn = 0; fn < 4; ++fn) {
      const int col = bcol * 128 + wc * 64 + fn * 16 + lm;
      if (col < N) {
#pragma unroll
        for (int r = 0; r < 4; ++r) {
          const float v = acc[fm][fn][r];
          if (BF16_OUT) ((unsigned short*)C)[(size_t)(row + r) * ldc + col] = f2bf(v);
          else          ((float*)C)[(size_t)(row + r) * ldc + col] = v;
        }
      }
    }
  }
}

// ---------------- weight transpose + cast: WT[n][k] = bf16(W[k][n]) ----------------
__global__ __launch_bounds__(256) void transpose_cast(
    const float* __restrict__ W, unsigned short* __restrict__ WT, int K, int N)
{
  __shared__ float tl[64][65];
  const int n0 = blockIdx.x * 64, k0 = blockIdx.y * 64;
  const int t = threadIdx.x;
  const int c = t & 63, rb = t >> 6;
#pragma unroll
  for (int i = 0; i < 16; ++i) {
    const int r = i * 4 + rb;
    tl[r][c] = W[(size_t)(k0 + r) * N + n0 + c];
  }
  __syncthreads();
#pragma unroll
  for (int i = 0; i < 16; ++i) {
    const int r = i * 4 + rb;
    WT[(size_t)(n0 + r) * K + k0 + c] = f2bf(tl[c][r]);
  }
}

// ---------------- elementwise fp32 -> bf16 ----------------
__global__ __launch_bounds__(256) void cast_bf16(
    const float* __restrict__ x, unsigned short* __restrict__ y, int n8)
{
  const int i = blockIdx.x * 256 + threadIdx.x;
  if (i >= n8) return;
  const float4 a = ((const float4*)x)[i * 2];
  const float4 b = ((const float4*)x)[i * 2 + 1];
  u16x8 o;
  o[0] = f2bf(a.x); o[1] = f2bf(a.y); o[2] = f2bf(a.z); o[3] = f2bf(a.w);
  o[4] = f2bf(b.x); o[5] = f2bf(b.y); o[6] = f2bf(b.z); o[7] = f2bf(b.w);
  ((u16x8*)y)[i] = o;
}

// ---------------- RMSNorm fp32 row -> bf16 row ----------------
__global__ __launch_bounds__(256) void rmsnorm_cast(
    const float* __restrict__ x, const float* __restrict__ w,
    unsigned short* __restrict__ y, int N, int ld)
{
  const int r = blockIdx.x;
  const float* row = x + (size_t)r * ld;
  const int t = threadIdx.x;
  const int nf4 = N >> 2;
  float4 v[2]; int cnt = 0; float ss = 0.f;
  for (int i = t; i < nf4; i += 256) {
    float4 vv = ((const float4*)row)[i];
    v[cnt++] = vv;
    ss += vv.x * vv.x + vv.y * vv.y + vv.z * vv.z + vv.w * vv.w;
  }
#pragma unroll
  for (int off = 32; off; off >>= 1) ss += __shfl_xor(ss, off, 64);
  __shared__ float red[4];
  if ((t & 63) == 0) red[t >> 6] = ss;
  __syncthreads();
  ss = red[0] + red[1] + red[2] + red[3];
  const float rn = rsqrtf(ss / (float)N + 1e-6f);
  unsigned short* yrow = y + (size_t)r * N;
  cnt = 0;
  for (int i = t; i < nf4; i += 256) {
    float4 vv = v[cnt++];
    float4 wv = ((const float4*)w)[i];
    ushort4 o = make_ushort4(f2bf(vv.x * rn * wv.x), f2bf(vv.y * rn * wv.y),
                             f2bf(vv.z * rn * wv.z), f2bf(vv.w * rn * wv.w));
    ((ushort4*)yrow)[i] = o;
  }
}

// ---------------- RoPE tables (double-precision inv_freq) ----------------
__global__ __launch_bounds__(256) void rope_tables(float* __restrict__ ct, float* __restrict__ st)
{
  const int idx = blockIdx.x * 256 + threadIdx.x;   // S_LEN*32
  const int s = idx >> 5, j = idx & 31;
  const double inv = exp(-((double)(2 * j) / 64.0) * log(25600000.0));
  const float freq = (float)s * (float)inv;
  ct[idx] = cosf(freq);
  st[idx] = sinf(freq);
}

// ---------------- RoPE apply: q_pe (bf16, in place), k_pe (f32 latent -> f32 kpe) ----------------
__global__ __launch_bounds__(256) void rope_apply(
    unsigned short* __restrict__ q, const float* __restrict__ latent, float* __restrict__ kpe,
    const float* __restrict__ ct, const float* __restrict__ st, const int* __restrict__ pid)
{
  const int s = blockIdx.x;
  __shared__ float qs[2048];          // 32 heads x 64 rope dims
  const int t = threadIdx.x;
#pragma unroll
  for (int i = 0; i < 8; ++i) {
    const int idx = t + i * 256;
    const int hh = idx >> 6, d = idx & 63;
    qs[idx] = bf2f(q[(size_t)s * HQ + hh * DQK + 128 + d]);
  }
  __syncthreads();
  const int pos = pid[s];
#pragma unroll
  for (int i = 0; i < 4; ++i) {
    const int wi = t + i * 256;       // 32 heads x 32 pairs
    const int hh = wi >> 5, j = wi & 31;
    const float c = ct[pos * 32 + j], sn = st[pos * 32 + j];
    const float x0 = qs[hh * 64 + 2 * j], x1 = qs[hh * 64 + 2 * j + 1];
    q[(size_t)s * HQ + hh * DQK + 128 + j]      = f2bf(x0 * c - x1 * sn);
    q[(size_t)s * HQ + hh * DQK + 128 + 32 + j] = f2bf(x1 * c + x0 * sn);
  }
  if (t < 32) {
    const int j = t;
    const float c = ct[pos * 32 + j], sn = st[pos * 32 + j];
    const float x0 = latent[(size_t)s * LATD + 512 + 2 * j];
    const float x1 = latent[(size_t)s * LATD + 512 + 2 * j + 1];
    kpe[(size_t)s * DROPE + j]      = x0 * c - x1 * sn;
    kpe[(size_t)s * DROPE + 32 + j] = x1 * c + x0 * sn;
  }
}

// ---------------- Flash attention, fp32 math, bf16 Q/K/V inputs ----------------
__global__ __launch_bounds__(256) void attn_flash(
    const unsigned short* __restrict__ q, const unsigned short* __restrict__ kv,
    const float* __restrict__ kpe, const float* __restrict__ mask,
    unsigned short* __restrict__ attnb)
{
  const int h = blockIdx.y;
  const int qb = gridDim.x - 1 - blockIdx.x;   // heavy blocks first
  const int Q0 = qb * 64;
  __shared__ float Qt[DQK][64];
  __shared__ float U[3328];
  __shared__ float mArr[64], lArr[64], aArr[64];
  float* Kt = U;            // [16][196]
  float* Vt = U;            // [16][128]
  float* Pp = U + 2048;     // [64][20]
  const int t = threadIdx.x;
  if (t < 64) { mArr[t] = -INFINITY; lArr[t] = 0.f; }
  const int tk = t & 15, tq = t >> 4;
  const int tdv = t & 31, tq2 = t >> 5;
  float accv[8][4];
#pragma unroll
  for (int r = 0; r < 8; ++r) { accv[r][0] = accv[r][1] = accv[r][2] = accv[r][3] = 0.f; }

  // stage Q tile transposed: Qt[d][qr], from bf16
#pragma unroll
  for (int i = 0; i < 6; ++i) {
    const int fl = t + i * 256;                // 1536 = 64 rows x 24 chunks of 8
    const int qr = fl / 24, c8 = fl % 24;
    u16x8 v = *(const u16x8*)&q[(size_t)(Q0 + qr) * HQ + h * DQK + c8 * 8];
#pragma unroll
    for (int j = 0; j < 8; ++j) Qt[c8 * 8 + j][qr] = bf2f((unsigned short)v[j]);
  }
  __syncthreads();

  const float scale = 0.07216878364870322f;    // 192^-0.5
  const int nc = (qb + 1) * 4;                 // causal
  for (int c = 0; c < nc; ++c) {
    const int k0 = c * 16;
    {  // K chunk (bf16) -> Kt[kr][0..127]
      const int kr = t >> 4, d8 = (t & 15) * 8;
      u16x8 v = *(const u16x8*)&kv[(size_t)(k0 + kr) * HKV + h * 256 + d8];
      float4 f0 = make_float4(bf2f((unsigned short)v[0]), bf2f((unsigned short)v[1]),
                              bf2f((unsigned short)v[2]), bf2f((unsigned short)v[3]));
      float4 f1 = make_float4(bf2f((unsigned short)v[4]), bf2f((unsigned short)v[5]),
                              bf2f((unsigned short)v[6]), bf2f((unsigned short)v[7]));
      *(float4*)&Kt[kr * 196 + d8] = f0;
      *(float4*)&Kt[kr * 196 + d8 + 4] = f1;
    }
    {  // rope part (f32) -> Kt[kr][128..191]
      const int kr = t >> 4, d4 = t & 15;
      float4 v = *(const float4*)&kpe[(size_t)(k0 + kr) * DROPE + d4 * 4];
      *(float4*)&Kt[kr * 196 + 128 + d4 * 4] = v;
    }
    __syncthreads();

    float s0 = 0.f, s1 = 0.f, s2 = 0.f, s3 = 0.f;
#pragma unroll 4
    for (int d = 0; d < DQK; d += 4) {
      float4 kq = *(const float4*)&Kt[tk * 196 + d];
      float4 q0 = *(const float4*)&Qt[d + 0][tq * 4];
      float4 q1 = *(const float4*)&Qt[d + 1][tq * 4];
      float4 q2 = *(const float4*)&Qt[d + 2][tq * 4];
      float4 q3 = *(const float4*)&Qt[d + 3][tq * 4];
      s0 = fmaf(q0.x, kq.x, s0); s0 = fmaf(q1.x, kq.y, s0); s0 = fmaf(q2.x, kq.z, s0); s0 = fmaf(q3.x, kq.w, s0);
      s1 = fmaf(q0.y, kq.x, s1); s1 = fmaf(q1.y, kq.y, s1); s1 = fmaf(q2.y, kq.z, s1); s1 = fmaf(q3.y, kq.w, s1);
      s2 = fmaf(q0.z, kq.x, s2); s2 = fmaf(q1.z, kq.y, s2); s2 = fmaf(q2.z, kq.z, s2); s2 = fmaf(q3.z, kq.w, s2);
      s3 = fmaf(q0.w, kq.x, s3); s3 = fmaf(q1.w, kq.y, s3); s3 = fmaf(q2.w, kq.z, s3); s3 = fmaf(q3.w, kq.w, s3);
    }
    float sv[4] = {s0, s1, s2, s3};
    float pv[4];
#pragma unroll
    for (int i = 0; i < 4; ++i) {
      const int row = tq * 4 + i;
      float x = sv[i] * scale + mask[(size_t)(Q0 + row) * S_LEN + k0 + tk];
      float rm = x;
      rm = fmaxf(rm, __shfl_xor(rm, 1, 16));
      rm = fmaxf(rm, __shfl_xor(rm, 2, 16));
      rm = fmaxf(rm, __shfl_xor(rm, 4, 16));
      rm = fmaxf(rm, __shfl_xor(rm, 8, 16));
      const float mo = mArr[row];
      const float mn = fmaxf(mo, rm);
      const float p = expf(x - mn);
      float rs = p;
      rs += __shfl_xor(rs, 1, 16);
      rs += __shfl_xor(rs, 2, 16);
      rs += __shfl_xor(rs, 4, 16);
      rs += __shfl_xor(rs, 8, 16);
      if (tk == 0) {
        const float al = expf(mo - mn);
        mArr[row] = mn; aArr[row] = al; lArr[row] = lArr[row] * al + rs;
      }
      pv[i] = p;
    }
    __syncthreads();

#pragma unroll
    for (int i = 0; i < 4; ++i) Pp[(tq * 4 + i) * 20 + tk] = pv[i];
    {  // V chunk (bf16) -> Vt
      const int vr = t >> 4, d8 = (t & 15) * 8;
      u16x8 v = *(const u16x8*)&kv[(size_t)(k0 + vr) * HKV + h * 256 + 128 + d8];
      float4 f0 = make_float4(bf2f((unsigned short)v[0]), bf2f((unsigned short)v[1]),
                              bf2f((unsigned short)v[2]), bf2f((unsigned short)v[3]));
      float4 f1 = make_float4(bf2f((unsigned short)v[4]), bf2f((unsigned short)v[5]),
                              bf2f((unsigned short)v[6]), bf2f((unsigned short)v[7]));
      *(float4*)&Vt[vr * 128 + d8] = f0;
      *(float4*)&Vt[vr * 128 + d8 + 4] = f1;
    }
    __syncthreads();

    float al[8];
#pragma unroll
    for (int r = 0; r < 8; ++r) al[r] = aArr[tq2 * 8 + r];
#pragma unroll
    for (int r = 0; r < 8; ++r) {
      accv[r][0] *= al[r]; accv[r][1] *= al[r]; accv[r][2] *= al[r]; accv[r][3] *= al[r];
    }
#pragma unroll
    for (int kk = 0; kk < 16; kk += 4) {
      float4 v0 = *(const float4*)&Vt[(kk + 0) * 128 + tdv * 4];
      float4 v1 = *(const float4*)&Vt[(kk + 1) * 128 + tdv * 4];
      float4 v2 = *(const float4*)&Vt[(kk + 2) * 128 + tdv * 4];
      float4 v3 = *(const float4*)&Vt[(kk + 3) * 128 + tdv * 4];
#pragma unroll
      for (int r = 0; r < 8; ++r) {
        float4 pf = *(const float4*)&Pp[(tq2 * 8 + r) * 20 + kk];
        accv[r][0] = fmaf(pf.x, v0.x, accv[r][0]); accv[r][0] = fmaf(pf.y, v1.x, accv[r][0]);
        accv[r][0] = fmaf(pf.z, v2.x, accv[r][0]); accv[r][0] = fmaf(pf.w, v3.x, accv[r][0]);
        accv[r][1] = fmaf(pf.x, v0.y, accv[r][1]); accv[r][1] = fmaf(pf.y, v1.y, accv[r][1]);
        accv[r][1] = fmaf(pf.z, v2.y, accv[r][1]); accv[r][1] = fmaf(pf.w, v3.y, accv[r][1]);
        accv[r][2] = fmaf(pf.x, v0.z, accv[r][2]); accv[r][2] = fmaf(pf.y, v1.z, accv[r][2]);
        accv[r][2] = fmaf(pf.z, v2.z, accv[r][2]); accv[r][2] = fmaf(pf.w, v3.z, accv[r][2]);
        accv[r][3] = fmaf(pf.x, v0.w, accv[r][3]); accv[r][3] = fmaf(pf.y, v1.w, accv[r][3]);
        accv[r][3] = fmaf(pf.z, v2.w, accv[r][3]); accv[r][3] = fmaf(pf.w, v3.w, accv[r][3]);
      }
    }
    __syncthreads();
  }

#pragma unroll
  for (int r = 0; r < 8; ++r) {
    const int row = tq2 * 8 + r;
    const float rl = 1.0f / lArr[row];
    ushort4 o = make_ushort4(f2bf(accv[r][0] * rl), f2bf(accv[r][1] * rl),
                             f2bf(accv[r][2] * rl), f2bf(accv[r][3] * rl));
    *(ushort4*)&attnb[(size_t)(Q0 + row) * HO + h * DV + tdv * 4] = o;
  }
}

// ---------------- launch ----------------
extern "C" void kernel_launch(void* const* d_in, const int* in_sizes, int n_in,
                              void* d_out, int out_size, void* d_ws, size_t ws_size,
                              hipStream_t stream) {
  const float* hidden = (const float*)d_in[0];
  const float* mask   = (const float*)d_in[1];
  const int*   pid    = (const int*)d_in[2];
  const float* Wq_a   = (const float*)d_in[3];
  const float* q_a_ln = (const float*)d_in[4];
  const float* Wq_b   = (const float*)d_in[5];
  const float* Wkv_a  = (const float*)d_in[6];
  const float* kv_a_ln= (const float*)d_in[7];
  const float* Wkv_b  = (const float*)d_in[8];
  const float* Wo     = (const float*)d_in[9];
  float* out = (float*)d_out;

  char* ws = (char*)d_ws;
  size_t off = 0;
  auto alloc = [&](size_t bytes) { char* p = ws + off; off += (bytes + 255) & ~(size_t)255; return p; };
  unsigned short* hid_bf = (unsigned short*)alloc((size_t)S_LEN * HIDN * 2);
  unsigned short* WqaT   = (unsigned short*)alloc((size_t)QLORA * HIDN * 2);
  unsigned short* WqbT   = (unsigned short*)alloc((size_t)HQ * QLORA * 2);
  unsigned short* WkvaT  = (unsigned short*)alloc((size_t)LATD * HIDN * 2);
  unsigned short* WkvbT  = (unsigned short*)alloc((size_t)HKV * KVLORA * 2);
  unsigned short* WoT    = (unsigned short*)alloc((size_t)HIDN * HO * 2);
  float* q_a    = (float*)alloc((size_t)S_LEN * QLORA * 4);
  unsigned short* qan   = (unsigned short*)alloc((size_t)S_LEN * QLORA * 2);
  float* latent = (float*)alloc((size_t)S_LEN * LATD * 4);
  unsigned short* kvn   = (unsigned short*)alloc((size_t)S_LEN * KVLORA * 2);
  unsigned short* qbuf  = (unsigned short*)alloc((size_t)S_LEN * HQ * 2);
  unsigned short* kvbuf = (unsigned short*)alloc((size_t)S_LEN * HKV * 2);
  float* kpe    = (float*)alloc((size_t)S_LEN * DROPE * 4);
  float* ct     = (float*)alloc((size_t)S_LEN * 32 * 4);
  float* st     = (float*)alloc((size_t)S_LEN * 32 * 4);
  unsigned short* attnb = (unsigned short*)alloc((size_t)S_LEN * HO * 2);
  (void)ws_size; (void)in_sizes; (void)n_in; (void)out_size;

  // 0) casts / transposes
  cast_bf16<<<(S_LEN * HIDN / 8 + 255) / 256, 256, 0, stream>>>(hidden, hid_bf, S_LEN * HIDN / 8);
  transpose_cast<<<dim3(QLORA / 64, HIDN / 64), 256, 0, stream>>>(Wq_a, WqaT, HIDN, QLORA);
  transpose_cast<<<dim3(HQ / 64, QLORA / 64), 256, 0, stream>>>(Wq_b, WqbT, QLORA, HQ);
  transpose_cast<<<dim3(LATD / 64, HIDN / 64), 256, 0, stream>>>(Wkv_a, WkvaT, HIDN, LATD);
  transpose_cast<<<dim3(HKV / 64, KVLORA / 64), 256, 0, stream>>>(Wkv_b, WkvbT, KVLORA, HKV);
  transpose_cast<<<dim3(HO / 64, HIDN / 64), 256, 0, stream>>>(Wo, WoT, HIDN, HO);
  rope_tables<<<(S_LEN * 32) / 256, 256, 0, stream>>>(ct, st);

  // 1) q_a = hidden @ Wq_a (f32 out); latent = hidden @ Wkv_a (f32 out)
  gemm_bf16<false><<<dim3(QLORA / 128, S_LEN / 128), 256, 0, stream>>>(hid_bf, WqaT, q_a, QLORA, HIDN, HIDN, QLORA);
  gemm_bf16<false><<<dim3((LATD + 127) / 128, S_LEN / 128), 256, 0, stream>>>(hid_bf, WkvaT, latent, LATD, HIDN, HIDN, LATD);
  // 2) RMS norms -> bf16
  rmsnorm_cast<<<S_LEN, 256, 0, stream>>>(q_a, q_a_ln, qan, QLORA, QLORA);
  rmsnorm_cast<<<S_LEN, 256, 0, stream>>>(latent, kv_a_ln, kvn, KVLORA, LATD);
  // 3) q = qan @ Wq_b (bf16 out); kv = kvn @ Wkv_b (bf16 out)
  gemm_bf16<true><<<dim3(HQ / 128, S_LEN / 128), 256, 0, stream>>>(qan, WqbT, qbuf, HQ, QLORA, QLORA, HQ);
  gemm_bf16<true><<<dim3(HKV / 128, S_LEN / 128), 256, 0, stream>>>(kvn, WkvbT, kvbuf, HKV, KVLORA, KVLORA, HKV);
  // 4) RoPE
  rope_apply<<<S_LEN, 256, 0, stream>>>(qbuf, latent, kpe, ct, st, pid);
  // 5) attention (fp32 math)
  attn_flash<<<dim3(S_LEN / 64, NH), 256, 0, stream>>>(qbuf, kvbuf, kpe, mask, attnb);
  // 6) out = attnb @ Wo (f32 out)
  gemm_bf16<false><<<dim3(HO / 128, S_LEN / 128), 256, 0, stream>>>(attnb, WoT, out, HO, HIDN, HIDN, HO);
}

// Round 3
// 908.765 us; speedup vs baseline: 2.8761x; 2.8761x over previous
//
#include <hip/hip_runtime.h>

#define S_LEN 2048
#define HIDN 4096
#define NH 32
#define DQK 192
#define DROPE 64
#define DV 128
#define QLORA 1536
#define KVLORA 512
#define LATD 576      // KVLORA + ROPE
#define HQ 6144       // NH*DQK
#define HKV 8192      // NH*(128+128)
#define HO 4096       // NH*DV

typedef float f32x4 __attribute__((ext_vector_type(4)));
typedef float f32x16 __attribute__((ext_vector_type(16)));
typedef __bf16 bf16x8 __attribute__((ext_vector_type(8)));
typedef unsigned short u16x8 __attribute__((ext_vector_type(8)));
typedef unsigned short u16x4 __attribute__((ext_vector_type(4)));

__device__ __forceinline__ float bf2f(unsigned short u) {
  union { unsigned int i; float f; } v; v.i = (unsigned int)u << 16; return v.f;
}
__device__ __forceinline__ unsigned short f2bf(float f) {   // RNE, finite inputs
  unsigned int u = __float_as_uint(f);
  return (unsigned short)((u + 0x7fffu + ((u >> 16) & 1u)) >> 16);
}
__device__ __forceinline__ void g2l16(const void* g, void* l) {
  __builtin_amdgcn_global_load_lds((__attribute__((address_space(1))) void*)(void*)g,
                                   (__attribute__((address_space(3))) void*)l, 16, 0, 0);
}

// ---------------- bf16 MFMA GEMM: C[M,N] = A[M,K] @ BT[N,K]^T ----------------
template<bool BF16_OUT>
__global__ __launch_bounds__(256) void gemm_bf16(
    const unsigned short* __restrict__ A,   // bf16 [M,K] row-major
    const unsigned short* __restrict__ BT,  // bf16 [N,K] row-major
    void* __restrict__ C, int N, int K, int lda, int ldc)
{
  __shared__ __align__(16) unsigned short As[128][32];
  __shared__ __align__(16) unsigned short Bs[128][32];
  const int t = threadIdx.x;
  const int brow = blockIdx.y, bcol = blockIdx.x;
  const int wave = t >> 6, lane = t & 63;
  const int wr = wave >> 1, wc = wave & 1;       // 64x64 per wave
  const int lm = lane & 15, lk = lane >> 4;

  f32x4 acc[4][4];
#pragma unroll
  for (int i = 0; i < 4; ++i)
#pragma unroll
    for (int j = 0; j < 4; ++j) acc[i][j] = (f32x4){0.f, 0.f, 0.f, 0.f};

  for (int k0 = 0; k0 < K; k0 += 32) {
#pragma unroll
    for (int i = 0; i < 2; ++i) {                 // A tile: 128x32 bf16 = 8KB
      const int c = t + i * 256;
      const int r = c >> 2, ko = (c & 3) * 8;
      g2l16(A + (size_t)(brow * 128 + r) * lda + k0 + ko,
            (char*)&As[0][0] + i * 4096 + wave * 1024);
    }
#pragma unroll
    for (int i = 0; i < 2; ++i) {                 // B^T tile: 128x32
      const int c = t + i * 256;
      const int r = c >> 2, ko = (c & 3) * 8;
      int n = bcol * 128 + r; if (n > N - 1) n = N - 1;   // tail clamp
      g2l16(BT + (size_t)n * K + k0 + ko,
            (char*)&Bs[0][0] + i * 4096 + wave * 1024);
    }
    __syncthreads();
    bf16x8 af[4], bfv[4];
#pragma unroll
    for (int fm = 0; fm < 4; ++fm) af[fm] = *(const bf16x8*)&As[wr * 64 + fm * 16 + lm][lk * 8];
#pragma unroll
    for (int fn = 0; fn < 4; ++fn) bfv[fn] = *(const bf16x8*)&Bs[wc * 64 + fn * 16 + lm][lk * 8];
#pragma unroll
    for (int fm = 0; fm < 4; ++fm)
#pragma unroll
      for (int fn = 0; fn < 4; ++fn)
        acc[fm][fn] = __builtin_amdgcn_mfma_f32_16x16x32_bf16(af[fm], bfv[fn], acc[fm][fn], 0, 0, 0);
    __syncthreads();
  }

#pragma unroll
  for (int fm = 0; fm < 4; ++fm) {
    const int row = brow * 128 + wr * 64 + fm * 16 + lk * 4;
#pragma unroll
    for (int fn = 0; fn < 4; ++fn) {
      const int col = bcol * 128 + wc * 64 + fn * 16 + lm;
      if (col < N) {
#pragma unroll
        for (int r = 0; r < 4; ++r) {
          const float v = acc[fm][fn][r];
          if (BF16_OUT) ((unsigned short*)C)[(size_t)(row + r) * ldc + col] = f2bf(v);
          else          ((float*)C)[(size_t)(row + r) * ldc + col] = v;
        }
      }
    }
  }
}

// ---------------- weight transpose + cast ----------------
__global__ __launch_bounds__(256) void transpose_cast(
    const float* __restrict__ W, unsigned short* __restrict__ WT, int K, int N)
{
  __shared__ float tl[64][65];
  const int n0 = blockIdx.x * 64, k0 = blockIdx.y * 64;
  const int t = threadIdx.x;
  const int c = t & 63, rb = t >> 6;
#pragma unroll
  for (int i = 0; i < 16; ++i) {
    const int r = i * 4 + rb;
    tl[r][c] = W[(size_t)(k0 + r) * N + n0 + c];
  }
  __syncthreads();
#pragma unroll
  for (int i = 0; i < 16; ++i) {
    const int r = i * 4 + rb;
    WT[(size_t)(n0 + r) * K + k0 + c] = f2bf(tl[c][r]);
  }
}

// ---------------- elementwise fp32 -> bf16 ----------------
__global__ __launch_bounds__(256) void cast_bf16(
    const float* __restrict__ x, unsigned short* __restrict__ y, int n8)
{
  const int i = blockIdx.x * 256 + threadIdx.x;
  if (i >= n8) return;
  const float4 a = ((const float4*)x)[i * 2];
  const float4 b = ((const float4*)x)[i * 2 + 1];
  u16x8 o;
  o[0] = f2bf(a.x); o[1] = f2bf(a.y); o[2] = f2bf(a.z); o[3] = f2bf(a.w);
  o[4] = f2bf(b.x); o[5] = f2bf(b.y); o[6] = f2bf(b.z); o[7] = f2bf(b.w);
  ((u16x8*)y)[i] = o;
}

// ---------------- RMSNorm fp32 row -> bf16 row ----------------
__global__ __launch_bounds__(256) void rmsnorm_cast(
    const float* __restrict__ x, const float* __restrict__ w,
    unsigned short* __restrict__ y, int N, int ld)
{
  const int r = blockIdx.x;
  const float* row = x + (size_t)r * ld;
  const int t = threadIdx.x;
  const int nf4 = N >> 2;
  float4 v[2]; int cnt = 0; float ss = 0.f;
  for (int i = t; i < nf4; i += 256) {
    float4 vv = ((const float4*)row)[i];
    v[cnt++] = vv;
    ss += vv.x * vv.x + vv.y * vv.y + vv.z * vv.z + vv.w * vv.w;
  }
#pragma unroll
  for (int off = 32; off; off >>= 1) ss += __shfl_xor(ss, off, 64);
  __shared__ float red[4];
  if ((t & 63) == 0) red[t >> 6] = ss;
  __syncthreads();
  ss = red[0] + red[1] + red[2] + red[3];
  const float rn = rsqrtf(ss / (float)N + 1e-6f);
  unsigned short* yrow = y + (size_t)r * N;
  cnt = 0;
  for (int i = t; i < nf4; i += 256) {
    float4 vv = v[cnt++];
    float4 wv = ((const float4*)w)[i];
    ushort4 o = make_ushort4(f2bf(vv.x * rn * wv.x), f2bf(vv.y * rn * wv.y),
                             f2bf(vv.z * rn * wv.z), f2bf(vv.w * rn * wv.w));
    ((ushort4*)yrow)[i] = o;
  }
}

// ---------------- RoPE tables (double-precision inv_freq) ----------------
__global__ __launch_bounds__(256) void rope_tables(float* __restrict__ ct, float* __restrict__ st)
{
  const int idx = blockIdx.x * 256 + threadIdx.x;   // S_LEN*32
  const int s = idx >> 5, j = idx & 31;
  const double inv = exp(-((double)(2 * j) / 64.0) * log(25600000.0));
  const float freq = (float)s * (float)inv;
  ct[idx] = cosf(freq);
  st[idx] = sinf(freq);
}

// ---------------- RoPE apply: q_pe (bf16 in place), k_pe -> bf16 kpe ----------------
__global__ __launch_bounds__(256) void rope_apply(
    unsigned short* __restrict__ q, const float* __restrict__ latent, unsigned short* __restrict__ kpe,
    const float* __restrict__ ct, const float* __restrict__ st, const int* __restrict__ pid)
{
  const int s = blockIdx.x;
  __shared__ float qs[2048];          // 32 heads x 64 rope dims
  const int t = threadIdx.x;
#pragma unroll
  for (int i = 0; i < 8; ++i) {
    const int idx = t + i * 256;
    const int hh = idx >> 6, d = idx & 63;
    qs[idx] = bf2f(q[(size_t)s * HQ + hh * DQK + 128 + d]);
  }
  __syncthreads();
  const int pos = pid[s];
#pragma unroll
  for (int i = 0; i < 4; ++i) {
    const int wi = t + i * 256;       // 32 heads x 32 pairs
    const int hh = wi >> 5, j = wi & 31;
    const float c = ct[pos * 32 + j], sn = st[pos * 32 + j];
    const float x0 = qs[hh * 64 + 2 * j], x1 = qs[hh * 64 + 2 * j + 1];
    q[(size_t)s * HQ + hh * DQK + 128 + j]      = f2bf(x0 * c - x1 * sn);
    q[(size_t)s * HQ + hh * DQK + 128 + 32 + j] = f2bf(x1 * c + x0 * sn);
  }
  if (t < 32) {
    const int j = t;
    const float c = ct[pos * 32 + j], sn = st[pos * 32 + j];
    const float x0 = latent[(size_t)s * LATD + 512 + 2 * j];
    const float x1 = latent[(size_t)s * LATD + 512 + 2 * j + 1];
    kpe[(size_t)s * DROPE + j]      = f2bf(x0 * c - x1 * sn);
    kpe[(size_t)s * DROPE + 32 + j] = f2bf(x1 * c + x0 * sn);
  }
}

// ---------------- MFMA flash attention ----------------
// 4 waves, q-tile 128 (32 q/wave), KV chunk 64, 32x32x16 bf16 MFMA.
// S^T = mfma(K, Q): C col=lane&31 = q (lane-local softmax state), row = kv.
// LDS: Kt [64][192] swizzled (24576B) + Vt [128][64] swizzled (16384B)
//    + P  [4 waves][32][64] swizzled (16384B) = 57344B -> 2 blocks/CU.
#define KT_OFF 0
#define VT_OFF 24576
#define P_OFF  40960

__global__ __launch_bounds__(256) void attn_mfma(
    const unsigned short* __restrict__ q,      // bf16 [S][HQ]
    const unsigned short* __restrict__ kv,     // bf16 [S][HKV]
    const unsigned short* __restrict__ kpe,    // bf16 [S][64]
    const float* __restrict__ mask,            // f32 [S][S]
    unsigned short* __restrict__ attnb)        // bf16 [S][HO]
{
  __shared__ __align__(16) char lds[57344];
  const int h = blockIdx.y, qb = blockIdx.x;
  const int Q0 = qb * 128;
  const int t = threadIdx.x;
  const int wq = t >> 6, lane = t & 63;
  const int lq = lane & 31, lh = lane >> 5;
  const int gq = Q0 + wq * 32 + lq;
  const float scale = 0.07216878364870322f;    // 192^-0.5

  // Q fragments: 12 k-frags of 16 (lane: row=lq, k=lh*8+j). Held in regs all kernel.
  bf16x8 qf[12];
#pragma unroll
  for (int f = 0; f < 12; ++f)
    qf[f] = *(const bf16x8*)&q[(size_t)gq * HQ + h * DQK + f * 16 + lh * 8];

  f32x16 acc0, acc1, acc2, acc3;
#pragma unroll
  for (int i = 0; i < 16; ++i) { acc0[i] = 0.f; acc1[i] = 0.f; acc2[i] = 0.f; acc3[i] = 0.f; }
  float m = -INFINITY, l = 0.f;

  // staging thread roles
  const int kA = t >> 2, cA = t & 3;          // K nope: row kA, chunk cA+4i
  const int kR = t & 63, cR = t >> 6;         // K rope
  const int kV = t & 63, dV = (t >> 6) * 8;   // V transpose

  const int nc = 2 * qb + 2;
  for (int c = 0; c < nc; ++c) {
    const int k0 = c * 64;
    __syncthreads();                          // prev chunk's reads done
    // ---- stage K rows [64][192] bf16, byte ^= (kv&7)<<4 ----
    {
      const unsigned short* src = &kv[(size_t)(k0 + kA) * HKV + h * 256];
      const int sw = (kA & 7) << 4;
#pragma unroll
      for (int i = 0; i < 4; ++i) {
        u16x8 v = *(const u16x8*)&src[(cA + 4 * i) * 8];
        *(u16x8*)&lds[KT_OFF + ((kA * 384 + (cA + 4 * i) * 16) ^ sw)] = v;
      }
    }
    {
      const unsigned short* src = &kpe[(size_t)(k0 + kR) * DROPE];
      const int sw = (kR & 7) << 4;
#pragma unroll
      for (int i = 0; i < 2; ++i) {
        u16x8 v = *(const u16x8*)&src[(cR + 4 * i) * 8];
        *(u16x8*)&lds[KT_OFF + ((kR * 384 + (16 + cR + 4 * i) * 16) ^ sw)] = v;
      }
    }
    // ---- stage V^T [128 dv][64 kv], byte ^= (dv&7)<<4 ----
    {
      const unsigned short* src = &kv[(size_t)(k0 + kV) * HKV + h * 256 + 128];
#pragma unroll
      for (int i = 0; i < 4; ++i) {
        u16x8 v = *(const u16x8*)&src[dV + 32 * i];
#pragma unroll
        for (int j = 0; j < 8; ++j) {
          const int dv = dV + 32 * i + j;
          *(unsigned short*)&lds[VT_OFF + ((dv * 128 + kV * 2) ^ ((dv & 7) << 4))] =
              (unsigned short)v[j];
        }
      }
    }
    __syncthreads();                          // staged

    // ---- S^T = K · Q^T : 2 kv-frags x 12 k-frags ----
    f32x16 s0, s1;
#pragma unroll
    for (int i = 0; i < 16; ++i) { s0[i] = 0.f; s1[i] = 0.f; }
    {
      const int sw0 = (lq & 7) << 4;
#pragma unroll
      for (int kf = 0; kf < 12; ++kf) {
        bf16x8 a0 = *(const bf16x8*)&lds[KT_OFF + ((lq * 384 + kf * 32 + lh * 16) ^ sw0)];
        s0 = __builtin_amdgcn_mfma_f32_32x32x16_bf16(a0, qf[kf], s0, 0, 0, 0);
      }
#pragma unroll
      for (int kf = 0; kf < 12; ++kf) {
        bf16x8 a1 = *(const bf16x8*)&lds[KT_OFF + (((32 + lq) * 384 + kf * 32 + lh * 16) ^ sw0)];
        s1 = __builtin_amdgcn_mfma_f32_32x32x16_bf16(a1, qf[kf], s1, 0, 0, 0);
      }
    }

    // ---- online softmax (lane owns column q=gq; kv = (r&3)+8(r>>2)+4lh+32*frag) ----
    float x0[16], x1[16];
    if (c >= nc - 2) {                        // diagonal chunks: read real mask
#pragma unroll
      for (int r = 0; r < 4; ++r) {
        const float4 mv0 = *(const float4*)&mask[(size_t)gq * S_LEN + k0 + 8 * r + 4 * lh];
        const float4 mv1 = *(const float4*)&mask[(size_t)gq * S_LEN + k0 + 32 + 8 * r + 4 * lh];
        x0[4 * r + 0] = s0[4 * r + 0] * scale + mv0.x;
        x0[4 * r + 1] = s0[4 * r + 1] * scale + mv0.y;
        x0[4 * r + 2] = s0[4 * r + 2] * scale + mv0.z;
        x0[4 * r + 3] = s0[4 * r + 3] * scale + mv0.w;
        x1[4 * r + 0] = s1[4 * r + 0] * scale + mv1.x;
        x1[4 * r + 1] = s1[4 * r + 1] * scale + mv1.y;
        x1[4 * r + 2] = s1[4 * r + 2] * scale + mv1.z;
        x1[4 * r + 3] = s1[4 * r + 3] * scale + mv1.w;
      }
    } else {
#pragma unroll
      for (int i = 0; i < 16; ++i) { x0[i] = s0[i] * scale; x1[i] = s1[i] * scale; }
    }
    float cm = x0[0];
#pragma unroll
    for (int i = 1; i < 16; ++i) cm = fmaxf(cm, x0[i]);
#pragma unroll
    for (int i = 0; i < 16; ++i) cm = fmaxf(cm, x1[i]);
    cm = fmaxf(cm, __shfl_xor(cm, 32, 64));
    const float mn = fmaxf(m, cm);
    const float alpha = __expf(m - mn);
    m = mn;
    float ps = 0.f;
#pragma unroll
    for (int i = 0; i < 16; ++i) { x0[i] = __expf(x0[i] - mn); ps += x0[i]; }
#pragma unroll
    for (int i = 0; i < 16; ++i) { x1[i] = __expf(x1[i] - mn); ps += x1[i]; }
    ps += __shfl_xor(ps, 32, 64);
    l = l * alpha + ps;

    // rescale acc by alpha of its OUTPUT row (regs span 16 q-rows != lq)
#pragma unroll
    for (int r = 0; r < 16; ++r) {
      const int qrow = (r & 3) + 8 * (r >> 2) + 4 * lh;
      const float af = __shfl(alpha, qrow, 32);
      acc0[r] *= af; acc1[r] *= af; acc2[r] *= af; acc3[r] *= af;
    }

    // ---- P -> LDS bf16 [32 q][64 kv] swizzled; reg-quads are 4 consecutive kv ----
    {
      char* pb = &lds[P_OFF + wq * 4096];
      const int sw = (lq & 7) << 4;
#pragma unroll
      for (int r = 0; r < 4; ++r) {
        u16x4 pk;
        pk[0] = f2bf(x0[4 * r + 0]); pk[1] = f2bf(x0[4 * r + 1]);
        pk[2] = f2bf(x0[4 * r + 2]); pk[3] = f2bf(x0[4 * r + 3]);
        *(u16x4*)&pb[(lq * 128 + 16 * r + 8 * lh) ^ sw] = pk;
        pk[0] = f2bf(x1[4 * r + 0]); pk[1] = f2bf(x1[4 * r + 1]);
        pk[2] = f2bf(x1[4 * r + 2]); pk[3] = f2bf(x1[4 * r + 3]);
        *(u16x4*)&pb[(lq * 128 + 64 + 16 * r + 8 * lh) ^ sw] = pk;
      }
    }

    // ---- PV: out += P[32q x 64kv] @ Vt[128dv x 64kv]^T ----
    {
      const char* pb = &lds[P_OFF + wq * 4096];
      const int sw = (lq & 7) << 4;
#pragma unroll
      for (int kf = 0; kf < 4; ++kf) {
        bf16x8 pa = *(const bf16x8*)&pb[(lq * 128 + kf * 32 + lh * 16) ^ sw];
        bf16x8 v0 = *(const bf16x8*)&lds[VT_OFF + (((0 * 32 + lq) * 128 + kf * 32 + lh * 16) ^ sw)];
        bf16x8 v1 = *(const bf16x8*)&lds[VT_OFF + (((1 * 32 + lq) * 128 + kf * 32 + lh * 16) ^ sw)];
        bf16x8 v2 = *(const bf16x8*)&lds[VT_OFF + (((2 * 32 + lq) * 128 + kf * 32 + lh * 16) ^ sw)];
        bf16x8 v3 = *(const bf16x8*)&lds[VT_OFF + (((3 * 32 + lq) * 128 + kf * 32 + lh * 16) ^ sw)];
        acc0 = __builtin_amdgcn_mfma_f32_32x32x16_bf16(pa, v0, acc0, 0, 0, 0);
        acc1 = __builtin_amdgcn_mfma_f32_32x32x16_bf16(pa, v1, acc1, 0, 0, 0);
        acc2 = __builtin_amdgcn_mfma_f32_32x32x16_bf16(pa, v2, acc2, 0, 0, 0);
        acc3 = __builtin_amdgcn_mfma_f32_32x32x16_bf16(pa, v3, acc3, 0, 0, 0);
      }
    }
  }

  // ---- epilogue: divide by l (per output row, via shuffle), write bf16 ----
#pragma unroll
  for (int r = 0; r < 16; ++r) {
    const int qrow = (r & 3) + 8 * (r >> 2) + 4 * lh;
    const float rl = 1.0f / __shfl(l, qrow, 32);
    unsigned short* orow = &attnb[(size_t)(Q0 + wq * 32 + qrow) * HO + h * DV + lq];
    orow[0]  = f2bf(acc0[r] * rl);
    orow[32] = f2bf(acc1[r] * rl);
    orow[64] = f2bf(acc2[r] * rl);
    orow[96] = f2bf(acc3[r] * rl);
  }
}

// ---------------- launch ----------------
extern "C" void kernel_launch(void* const* d_in, const int* in_sizes, int n_in,
                              void* d_out, int out_size, void* d_ws, size_t ws_size,
                              hipStream_t stream) {
  const float* hidden = (const float*)d_in[0];
  const float* mask   = (const float*)d_in[1];
  const int*   pid    = (const int*)d_in[2];
  const float* Wq_a   = (const float*)d_in[3];
  const float* q_a_ln = (const float*)d_in[4];
  const float* Wq_b   = (const float*)d_in[5];
  const float* Wkv_a  = (const float*)d_in[6];
  const float* kv_a_ln= (const float*)d_in[7];
  const float* Wkv_b  = (const float*)d_in[8];
  const float* Wo     = (const float*)d_in[9];
  float* out = (float*)d_out;

  char* ws = (char*)d_ws;
  size_t off = 0;
  auto alloc = [&](size_t bytes) { char* p = ws + off; off += (bytes + 255) & ~(size_t)255; return p; };
  unsigned short* hid_bf = (unsigned short*)alloc((size_t)S_LEN * HIDN * 2);
  unsigned short* WqaT   = (unsigned short*)alloc((size_t)QLORA * HIDN * 2);
  unsigned short* WqbT   = (unsigned short*)alloc((size_t)HQ * QLORA * 2);
  unsigned short* WkvaT  = (unsigned short*)alloc((size_t)LATD * HIDN * 2);
  unsigned short* WkvbT  = (unsigned short*)alloc((size_t)HKV * KVLORA * 2);
  unsigned short* WoT    = (unsigned short*)alloc((size_t)HIDN * HO * 2);
  float* q_a    = (float*)alloc((size_t)S_LEN * QLORA * 4);
  unsigned short* qan   = (unsigned short*)alloc((size_t)S_LEN * QLORA * 2);
  float* latent = (float*)alloc((size_t)S_LEN * LATD * 4);
  unsigned short* kvn   = (unsigned short*)alloc((size_t)S_LEN * KVLORA * 2);
  unsigned short* qbuf  = (unsigned short*)alloc((size_t)S_LEN * HQ * 2);
  unsigned short* kvbuf = (unsigned short*)alloc((size_t)S_LEN * HKV * 2);
  unsigned short* kpe   = (unsigned short*)alloc((size_t)S_LEN * DROPE * 2);
  float* ct     = (float*)alloc((size_t)S_LEN * 32 * 4);
  float* st     = (float*)alloc((size_t)S_LEN * 32 * 4);
  unsigned short* attnb = (unsigned short*)alloc((size_t)S_LEN * HO * 2);
  (void)ws_size; (void)in_sizes; (void)n_in; (void)out_size;

  // 0) casts / transposes / tables
  cast_bf16<<<(S_LEN * HIDN / 8 + 255) / 256, 256, 0, stream>>>(hidden, hid_bf, S_LEN * HIDN / 8);
  transpose_cast<<<dim3(QLORA / 64, HIDN / 64), 256, 0, stream>>>(Wq_a, WqaT, HIDN, QLORA);
  transpose_cast<<<dim3(HQ / 64, QLORA / 64), 256, 0, stream>>>(Wq_b, WqbT, QLORA, HQ);
  transpose_cast<<<dim3(LATD / 64, HIDN / 64), 256, 0, stream>>>(Wkv_a, WkvaT, HIDN, LATD);
  transpose_cast<<<dim3(HKV / 64, KVLORA / 64), 256, 0, stream>>>(Wkv_b, WkvbT, KVLORA, HKV);
  transpose_cast<<<dim3(HO / 64, HIDN / 64), 256, 0, stream>>>(Wo, WoT, HIDN, HO);
  rope_tables<<<(S_LEN * 32) / 256, 256, 0, stream>>>(ct, st);

  // 1) projections
  gemm_bf16<false><<<dim3(QLORA / 128, S_LEN / 128), 256, 0, stream>>>(hid_bf, WqaT, q_a, QLORA, HIDN, HIDN, QLORA);
  gemm_bf16<false><<<dim3((LATD + 127) / 128, S_LEN / 128), 256, 0, stream>>>(hid_bf, WkvaT, latent, LATD, HIDN, HIDN, LATD);
  // 2) RMS norms -> bf16
  rmsnorm_cast<<<S_LEN, 256, 0, stream>>>(q_a, q_a_ln, qan, QLORA, QLORA);
  rmsnorm_cast<<<S_LEN, 256, 0, stream>>>(latent, kv_a_ln, kvn, KVLORA, LATD);
  // 3) up-projections
  gemm_bf16<true><<<dim3(HQ / 128, S_LEN / 128), 256, 0, stream>>>(qan, WqbT, qbuf, HQ, QLORA, QLORA, HQ);
  gemm_bf16<true><<<dim3(HKV / 128, S_LEN / 128), 256, 0, stream>>>(kvn, WkvbT, kvbuf, HKV, KVLORA, KVLORA, HKV);
  // 4) RoPE
  rope_apply<<<S_LEN, 256, 0, stream>>>(qbuf, latent, kpe, ct, st, pid);
  // 5) MFMA flash attention
  attn_mfma<<<dim3(S_LEN / 128, NH), 256, 0, stream>>>(qbuf, kvbuf, kpe, mask, attnb);
  // 6) out = attnb @ Wo
  gemm_bf16<false><<<dim3(HO / 128, S_LEN / 128), 256, 0, stream>>>(attnb, WoT, out, HO, HIDN, HIDN, HO);
}

// Round 5
// 849.695 us; speedup vs baseline: 3.0761x; 1.0695x over previous
//
#include <hip/hip_runtime.h>

#define S_LEN 2048
#define HIDN 4096
#define NH 32
#define DQK 192
#define DROPE 64
#define DV 128
#define QLORA 1536
#define KVLORA 512
#define LATD 576      // KVLORA + ROPE
#define HQ 6144       // NH*DQK
#define HKV 8192      // NH*(128+128)
#define HO 4096       // NH*DV

typedef float f32x4 __attribute__((ext_vector_type(4)));
typedef float f32x16 __attribute__((ext_vector_type(16)));
typedef __bf16 bf16x8 __attribute__((ext_vector_type(8)));
typedef unsigned short u16x8 __attribute__((ext_vector_type(8)));
typedef unsigned short u16x4 __attribute__((ext_vector_type(4)));

__device__ __forceinline__ float bf2f(unsigned short u) {
  union { unsigned int i; float f; } v; v.i = (unsigned int)u << 16; return v.f;
}
__device__ __forceinline__ unsigned short f2bf(float f) {   // RNE, finite inputs
  unsigned int u = __float_as_uint(f);
  return (unsigned short)((u + 0x7fffu + ((u >> 16) & 1u)) >> 16);
}
__device__ __forceinline__ void g2l16(const void* g, void* l) {
  __builtin_amdgcn_global_load_lds((__attribute__((address_space(1))) void*)(void*)g,
                                   (__attribute__((address_space(3))) void*)l, 16, 0, 0);
}

// ---------------- bf16 MFMA GEMM: C[M,N] = A[M,K] @ BT[N,K]^T ----------------
template<bool BF16_OUT>
__global__ __launch_bounds__(256) void gemm_bf16(
    const unsigned short* __restrict__ A,   // bf16 [M,K] row-major
    const unsigned short* __restrict__ BT,  // bf16 [N,K] row-major
    void* __restrict__ C, int N, int K, int lda, int ldc)
{
  __shared__ __align__(16) unsigned short As[128][32];
  __shared__ __align__(16) unsigned short Bs[128][32];
  const int t = threadIdx.x;
  const int brow = blockIdx.y, bcol = blockIdx.x;
  const int wave = t >> 6, lane = t & 63;
  const int wr = wave >> 1, wc = wave & 1;       // 64x64 per wave
  const int lm = lane & 15, lk = lane >> 4;

  f32x4 acc[4][4];
#pragma unroll
  for (int i = 0; i < 4; ++i)
#pragma unroll
    for (int j = 0; j < 4; ++j) acc[i][j] = (f32x4){0.f, 0.f, 0.f, 0.f};

  for (int k0 = 0; k0 < K; k0 += 32) {
#pragma unroll
    for (int i = 0; i < 2; ++i) {                 // A tile: 128x32 bf16 = 8KB
      const int c = t + i * 256;
      const int r = c >> 2, ko = (c & 3) * 8;
      g2l16(A + (size_t)(brow * 128 + r) * lda + k0 + ko,
            (char*)&As[0][0] + i * 4096 + wave * 1024);
    }
#pragma unroll
    for (int i = 0; i < 2; ++i) {                 // B^T tile: 128x32
      const int c = t + i * 256;
      const int r = c >> 2, ko = (c & 3) * 8;
      int n = bcol * 128 + r; if (n > N - 1) n = N - 1;   // tail clamp
      g2l16(BT + (size_t)n * K + k0 + ko,
            (char*)&Bs[0][0] + i * 4096 + wave * 1024);
    }
    __syncthreads();
    bf16x8 af[4], bfv[4];
#pragma unroll
    for (int fm = 0; fm < 4; ++fm) af[fm] = *(const bf16x8*)&As[wr * 64 + fm * 16 + lm][lk * 8];
#pragma unroll
    for (int fn = 0; fn < 4; ++fn) bfv[fn] = *(const bf16x8*)&Bs[wc * 64 + fn * 16 + lm][lk * 8];
#pragma unroll
    for (int fm = 0; fm < 4; ++fm)
#pragma unroll
      for (int fn = 0; fn < 4; ++fn)
        acc[fm][fn] = __builtin_amdgcn_mfma_f32_16x16x32_bf16(af[fm], bfv[fn], acc[fm][fn], 0, 0, 0);
    __syncthreads();
  }

#pragma unroll
  for (int fm = 0; fm < 4; ++fm) {
    const int row = brow * 128 + wr * 64 + fm * 16 + lk * 4;
#pragma unroll
    for (int fn = 0; fn < 4; ++fn) {
      const int col = bcol * 128 + wc * 64 + fn * 16 + lm;
      if (col < N) {
#pragma unroll
        for (int r = 0; r < 4; ++r) {
          const float v = acc[fm][fn][r];
          if (BF16_OUT) ((unsigned short*)C)[(size_t)(row + r) * ldc + col] = f2bf(v);
          else          ((float*)C)[(size_t)(row + r) * ldc + col] = v;
        }
      }
    }
  }
}

// ---------------- weight transpose + cast ----------------
__global__ __launch_bounds__(256) void transpose_cast(
    const float* __restrict__ W, unsigned short* __restrict__ WT, int K, int N)
{
  __shared__ float tl[64][65];
  const int n0 = blockIdx.x * 64, k0 = blockIdx.y * 64;
  const int t = threadIdx.x;
  const int c = t & 63, rb = t >> 6;
#pragma unroll
  for (int i = 0; i < 16; ++i) {
    const int r = i * 4 + rb;
    tl[r][c] = W[(size_t)(k0 + r) * N + n0 + c];
  }
  __syncthreads();
#pragma unroll
  for (int i = 0; i < 16; ++i) {
    const int r = i * 4 + rb;
    WT[(size_t)(n0 + r) * K + k0 + c] = f2bf(tl[c][r]);
  }
}

// ---------------- elementwise fp32 -> bf16 ----------------
__global__ __launch_bounds__(256) void cast_bf16(
    const float* __restrict__ x, unsigned short* __restrict__ y, int n8)
{
  const int i = blockIdx.x * 256 + threadIdx.x;
  if (i >= n8) return;
  const float4 a = ((const float4*)x)[i * 2];
  const float4 b = ((const float4*)x)[i * 2 + 1];
  u16x8 o;
  o[0] = f2bf(a.x); o[1] = f2bf(a.y); o[2] = f2bf(a.z); o[3] = f2bf(a.w);
  o[4] = f2bf(b.x); o[5] = f2bf(b.y); o[6] = f2bf(b.z); o[7] = f2bf(b.w);
  ((u16x8*)y)[i] = o;
}

// ---------------- RMSNorm fp32 row -> bf16 row ----------------
__global__ __launch_bounds__(256) void rmsnorm_cast(
    const float* __restrict__ x, const float* __restrict__ w,
    unsigned short* __restrict__ y, int N, int ld)
{
  const int r = blockIdx.x;
  const float* row = x + (size_t)r * ld;
  const int t = threadIdx.x;
  const int nf4 = N >> 2;
  float4 v[2]; int cnt = 0; float ss = 0.f;
  for (int i = t; i < nf4; i += 256) {
    float4 vv = ((const float4*)row)[i];
    v[cnt++] = vv;
    ss += vv.x * vv.x + vv.y * vv.y + vv.z * vv.z + vv.w * vv.w;
  }
#pragma unroll
  for (int off = 32; off; off >>= 1) ss += __shfl_xor(ss, off, 64);
  __shared__ float red[4];
  if ((t & 63) == 0) red[t >> 6] = ss;
  __syncthreads();
  ss = red[0] + red[1] + red[2] + red[3];
  const float rn = rsqrtf(ss / (float)N + 1e-6f);
  unsigned short* yrow = y + (size_t)r * N;
  cnt = 0;
  for (int i = t; i < nf4; i += 256) {
    float4 vv = v[cnt++];
    float4 wv = ((const float4*)w)[i];
    ushort4 o = make_ushort4(f2bf(vv.x * rn * wv.x), f2bf(vv.y * rn * wv.y),
                             f2bf(vv.z * rn * wv.z), f2bf(vv.w * rn * wv.w));
    ((ushort4*)yrow)[i] = o;
  }
}

// ---------------- RoPE tables (double-precision inv_freq) ----------------
__global__ __launch_bounds__(256) void rope_tables(float* __restrict__ ct, float* __restrict__ st)
{
  const int idx = blockIdx.x * 256 + threadIdx.x;   // S_LEN*32
  const int s = idx >> 5, j = idx & 31;
  const double inv = exp(-((double)(2 * j) / 64.0) * log(25600000.0));
  const float freq = (float)s * (float)inv;
  ct[idx] = cosf(freq);
  st[idx] = sinf(freq);
}

// ---------------- RoPE apply: q_pe (bf16 in place), k_pe -> bf16 kpe ----------------
__global__ __launch_bounds__(256) void rope_apply(
    unsigned short* __restrict__ q, const float* __restrict__ latent, unsigned short* __restrict__ kpe,
    const float* __restrict__ ct, const float* __restrict__ st, const int* __restrict__ pid)
{
  const int s = blockIdx.x;
  __shared__ float qs[2048];          // 32 heads x 64 rope dims
  const int t = threadIdx.x;
#pragma unroll
  for (int i = 0; i < 8; ++i) {
    const int idx = t + i * 256;
    const int hh = idx >> 6, d = idx & 63;
    qs[idx] = bf2f(q[(size_t)s * HQ + hh * DQK + 128 + d]);
  }
  __syncthreads();
  const int pos = pid[s];
#pragma unroll
  for (int i = 0; i < 4; ++i) {
    const int wi = t + i * 256;       // 32 heads x 32 pairs
    const int hh = wi >> 5, j = wi & 31;
    const float c = ct[pos * 32 + j], sn = st[pos * 32 + j];
    const float x0 = qs[hh * 64 + 2 * j], x1 = qs[hh * 64 + 2 * j + 1];
    q[(size_t)s * HQ + hh * DQK + 128 + j]      = f2bf(x0 * c - x1 * sn);
    q[(size_t)s * HQ + hh * DQK + 128 + 32 + j] = f2bf(x1 * c + x0 * sn);
  }
  if (t < 32) {
    const int j = t;
    const float c = ct[pos * 32 + j], sn = st[pos * 32 + j];
    const float x0 = latent[(size_t)s * LATD + 512 + 2 * j];
    const float x1 = latent[(size_t)s * LATD + 512 + 2 * j + 1];
    kpe[(size_t)s * DROPE + j]      = f2bf(x0 * c - x1 * sn);
    kpe[(size_t)s * DROPE + 32 + j] = f2bf(x1 * c + x0 * sn);
  }
}

// ---------------- MFMA flash attention v2 ----------------
// 4 waves, q-tile 128 (32 q/wave), KV chunk 64, 32x32x16 bf16 MFMA.
// v2: balanced block pairing; K staged via global_load_lds with pre-swizzled
// source (async under PV); V prefetched to regs at chunk top, packed b64
// writes after PV; defer-rescale (THR=8).
// LDS: Kt [64][192] swz (24576B) + Vt [128][64] swz (16384B) + P [4][32][64] (16384B)
#define KT_OFF 0
#define VT_OFF 24576
#define P_OFF  40960

__global__ __launch_bounds__(256, 2) void attn_mfma(
    const unsigned short* __restrict__ q,      // bf16 [S][HQ]
    const unsigned short* __restrict__ kv,     // bf16 [S][HKV]
    const unsigned short* __restrict__ kpe,    // bf16 [S][64]
    const float* __restrict__ mask,            // f32 [S][S]
    unsigned short* __restrict__ attnb)        // bf16 [S][HO]
{
  __shared__ __align__(16) char lds[57344];
  const int bid = blockIdx.x;                  // 512 blocks
  const int h = bid & 31;
  const int g = (bid >> 5) & 7;
  const int qb = (bid < 256) ? (15 - g) : g;   // pair (b, b+256): qb sums to 15
  const int Q0 = qb * 128;
  const int t = threadIdx.x;
  const int wq = t >> 6, lane = t & 63;
  const int lq = lane & 31, lh = lane >> 5;
  const int gq = Q0 + wq * 32 + lq;
  const float scale = 0.07216878364870322f;    // 192^-0.5

  // ---- loop-invariant K staging descriptors (pre-swizzled source) ----
  // read side uses byte (row*384 + cs*16) ^ ((row&7)<<4); source permuted to match.
  int koff[6], kisk[6];
#pragma unroll
  for (int i = 0; i < 6; ++i) {
    const int s = i * 256 + t;                 // 16B slot in Kt (1536 slots)
    const int row = s / 24, csp = s - row * 24;
    const int cs = (csp & ~7) | ((csp & 7) ^ (row & 7));
    if (cs < 16) { koff[i] = row * (HKV * 2) + h * 512 + cs * 16; kisk[i] = 0; }
    else         { koff[i] = row * 128 + (cs - 16) * 16;          kisk[i] = 1; }
  }
  // V staging: thread owns kv rows vr0..vr0+3, dv block vd0..vd0+7
  const int vr0 = (t & 15) * 4;
  const int vd0 = (t >> 4) * 8;
  u16x8 vreg[4];

  // Q fragments (held in regs all kernel)
  bf16x8 qf[12];
#pragma unroll
  for (int f = 0; f < 12; ++f)
    qf[f] = *(const bf16x8*)&q[(size_t)gq * HQ + h * DQK + f * 16 + lh * 8];

  f32x16 acc0, acc1, acc2, acc3;
#pragma unroll
  for (int i = 0; i < 16; ++i) { acc0[i] = 0.f; acc1[i] = 0.f; acc2[i] = 0.f; acc3[i] = 0.f; }
  float m = -INFINITY, l = 0.f;

  const int nc = 2 * qb + 2;

#define STAGE_K(KN) do {                                                        \
    const char* kvc = (const char*)kv + ((size_t)(KN) * 64) * (HKV * 2);        \
    const char* kpc = (const char*)kpe + (size_t)(KN) * 64 * 128;               \
    _Pragma("unroll")                                                           \
    for (int i = 0; i < 6; ++i) {                                               \
      const char* src = kisk[i] ? (kpc + koff[i]) : (kvc + koff[i]);            \
      g2l16(src, (char*)lds + KT_OFF + (i * 256 + wq * 64) * 16);               \
    }                                                                           \
  } while (0)

#define LOAD_V(KN) do {                                                         \
    _Pragma("unroll")                                                           \
    for (int j = 0; j < 4; ++j)                                                 \
      vreg[j] = *(const u16x8*)&kv[(size_t)((KN) * 64 + vr0 + j) * HKV + h * 256 + 128 + vd0]; \
  } while (0)

#define WRITE_V() do {                                                          \
    _Pragma("unroll")                                                           \
    for (int j = 0; j < 8; ++j) {                                               \
      const int dv = vd0 + j;                                                   \
      const unsigned int lo = (unsigned int)(unsigned short)vreg[0][j] |        \
                              ((unsigned int)(unsigned short)vreg[1][j] << 16); \
      const unsigned int hi = (unsigned int)(unsigned short)vreg[2][j] |        \
                              ((unsigned int)(unsigned short)vreg[3][j] << 16); \
      *(uint2*)&lds[VT_OFF + ((dv * 128 + vr0 * 2) ^ ((dv & 7) << 4))] =        \
          make_uint2(lo, hi);                                                   \
    }                                                                           \
  } while (0)

  // ---- prologue: stage chunk 0 ----
  STAGE_K(0);
  LOAD_V(0);
  __syncthreads();                 // drains vmcnt: Kt in LDS, V in regs
  WRITE_V();
  __syncthreads();

  for (int c = 0; c < nc; ++c) {
    const int k0 = c * 64;
    const bool last = (c == nc - 1);
    if (!last) LOAD_V(c + 1);      // in flight under QK+softmax

    // ---- S^T = K · Q^T : 2 kv-frags x 12 k-frags ----
    f32x16 s0, s1;
#pragma unroll
    for (int i = 0; i < 16; ++i) { s0[i] = 0.f; s1[i] = 0.f; }
    {
      const int sw0 = (lq & 7) << 4;
#pragma unroll
      for (int kf = 0; kf < 12; ++kf) {
        bf16x8 a0 = *(const bf16x8*)&lds[KT_OFF + ((lq * 384 + kf * 32 + lh * 16) ^ sw0)];
        s0 = __builtin_amdgcn_mfma_f32_32x32x16_bf16(a0, qf[kf], s0, 0, 0, 0);
      }
#pragma unroll
      for (int kf = 0; kf < 12; ++kf) {
        bf16x8 a1 = *(const bf16x8*)&lds[KT_OFF + (((32 + lq) * 384 + kf * 32 + lh * 16) ^ sw0)];
        s1 = __builtin_amdgcn_mfma_f32_32x32x16_bf16(a1, qf[kf], s1, 0, 0, 0);
      }
    }

    // ---- online softmax (lane owns q-col gq; kv = (r&3)+8(r>>2)+4lh+32*frag) ----
    float x0[16], x1[16];
    if (c >= nc - 2) {                         // diagonal chunks: read real mask
#pragma unroll
      for (int r = 0; r < 4; ++r) {
        const float4 mv0 = *(const float4*)&mask[(size_t)gq * S_LEN + k0 + 8 * r + 4 * lh];
        const float4 mv1 = *(const float4*)&mask[(size_t)gq * S_LEN + k0 + 32 + 8 * r + 4 * lh];
        x0[4 * r + 0] = s0[4 * r + 0] * scale + mv0.x;
        x0[4 * r + 1] = s0[4 * r + 1] * scale + mv0.y;
        x0[4 * r + 2] = s0[4 * r + 2] * scale + mv0.z;
        x0[4 * r + 3] = s0[4 * r + 3] * scale + mv0.w;
        x1[4 * r + 0] = s1[4 * r + 0] * scale + mv1.x;
        x1[4 * r + 1] = s1[4 * r + 1] * scale + mv1.y;
        x1[4 * r + 2] = s1[4 * r + 2] * scale + mv1.z;
        x1[4 * r + 3] = s1[4 * r + 3] * scale + mv1.w;
      }
    } else {
#pragma unroll
      for (int i = 0; i < 16; ++i) { x0[i] = s0[i] * scale; x1[i] = s1[i] * scale; }
    }
    float cm = x0[0];
#pragma unroll
    for (int i = 1; i < 16; ++i) cm = fmaxf(cm, x0[i]);
#pragma unroll
    for (int i = 0; i < 16; ++i) cm = fmaxf(cm, x1[i]);
    cm = fmaxf(cm, __shfl_xor(cm, 32, 64));

    if (!__all(cm <= m + 8.0f)) {              // T13 defer-rescale (first chunk: m=-inf -> taken)
      const float mn = fmaxf(m, cm);
      const float alpha = __expf(m - mn);
      m = mn;
      l *= alpha;
#pragma unroll
      for (int r = 0; r < 16; ++r) {
        const int qrow = (r & 3) + 8 * (r >> 2) + 4 * lh;
        const float af = __shfl(alpha, qrow, 32);
        acc0[r] *= af; acc1[r] *= af; acc2[r] *= af; acc3[r] *= af;
      }
    }
    float ps = 0.f;
#pragma unroll
    for (int i = 0; i < 16; ++i) { x0[i] = __expf(x0[i] - m); ps += x0[i]; }
#pragma unroll
    for (int i = 0; i < 16; ++i) { x1[i] = __expf(x1[i] - m); ps += x1[i]; }
    ps += __shfl_xor(ps, 32, 64);
    l += ps;

    // ---- P -> LDS bf16 [32 q][64 kv] swizzled (wave-private region) ----
    {
      char* pb = &lds[P_OFF + wq * 4096];
      const int sw = (lq & 7) << 4;
#pragma unroll
      for (int r = 0; r < 4; ++r) {
        u16x4 pk;
        pk[0] = f2bf(x0[4 * r + 0]); pk[1] = f2bf(x0[4 * r + 1]);
        pk[2] = f2bf(x0[4 * r + 2]); pk[3] = f2bf(x0[4 * r + 3]);
        *(u16x4*)&pb[(lq * 128 + 16 * r + 8 * lh) ^ sw] = pk;
        pk[0] = f2bf(x1[4 * r + 0]); pk[1] = f2bf(x1[4 * r + 1]);
        pk[2] = f2bf(x1[4 * r + 2]); pk[3] = f2bf(x1[4 * r + 3]);
        *(u16x4*)&pb[(lq * 128 + 64 + 16 * r + 8 * lh) ^ sw] = pk;
      }
    }
    __syncthreads();                           // A: all waves done reading Kt
    if (!last) STAGE_K(c + 1);                 // async DMA under PV

    // ---- PV: out += P[32q x 64kv] @ Vt[128dv x 64kv]^T ----
    {
      const char* pb = &lds[P_OFF + wq * 4096];
      const int sw = (lq & 7) << 4;
#pragma unroll
      for (int kf = 0; kf < 4; ++kf) {
        bf16x8 pa = *(const bf16x8*)&pb[(lq * 128 + kf * 32 + lh * 16) ^ sw];
        bf16x8 v0 = *(const bf16x8*)&lds[VT_OFF + (((0 * 32 + lq) * 128 + kf * 32 + lh * 16) ^ sw)];
        bf16x8 v1 = *(const bf16x8*)&lds[VT_OFF + (((1 * 32 + lq) * 128 + kf * 32 + lh * 16) ^ sw)];
        bf16x8 v2 = *(const bf16x8*)&lds[VT_OFF + (((2 * 32 + lq) * 128 + kf * 32 + lh * 16) ^ sw)];
        bf16x8 v3 = *(const bf16x8*)&lds[VT_OFF + (((3 * 32 + lq) * 128 + kf * 32 + lh * 16) ^ sw)];
        acc0 = __builtin_amdgcn_mfma_f32_32x32x16_bf16(pa, v0, acc0, 0, 0, 0);
        acc1 = __builtin_amdgcn_mfma_f32_32x32x16_bf16(pa, v1, acc1, 0, 0, 0);
        acc2 = __builtin_amdgcn_mfma_f32_32x32x16_bf16(pa, v2, acc2, 0, 0, 0);
        acc3 = __builtin_amdgcn_mfma_f32_32x32x16_bf16(pa, v3, acc3, 0, 0, 0);
      }
    }
    if (!last) {
      __syncthreads();                         // B: Vt free; drains vmcnt (K DMA done, V regs ready)
      WRITE_V();
      __syncthreads();                         // C: chunk c+1 staged
    }
  }

  // ---- epilogue: divide by l (per output row, via shuffle), write bf16 ----
#pragma unroll
  for (int r = 0; r < 16; ++r) {
    const int qrow = (r & 3) + 8 * (r >> 2) + 4 * lh;
    const float rl = 1.0f / __shfl(l, qrow, 32);
    unsigned short* orow = &attnb[(size_t)(Q0 + wq * 32 + qrow) * HO + h * DV + lq];
    orow[0]  = f2bf(acc0[r] * rl);
    orow[32] = f2bf(acc1[r] * rl);
    orow[64] = f2bf(acc2[r] * rl);
    orow[96] = f2bf(acc3[r] * rl);
  }
#undef STAGE_K
#undef LOAD_V
#undef WRITE_V
}

// ---------------- launch ----------------
extern "C" void kernel_launch(void* const* d_in, const int* in_sizes, int n_in,
                              void* d_out, int out_size, void* d_ws, size_t ws_size,
                              hipStream_t stream) {
  const float* hidden = (const float*)d_in[0];
  const float* mask   = (const float*)d_in[1];
  const int*   pid    = (const int*)d_in[2];
  const float* Wq_a   = (const float*)d_in[3];
  const float* q_a_ln = (const float*)d_in[4];
  const float* Wq_b   = (const float*)d_in[5];
  const float* Wkv_a  = (const float*)d_in[6];
  const float* kv_a_ln= (const float*)d_in[7];
  const float* Wkv_b  = (const float*)d_in[8];
  const float* Wo     = (const float*)d_in[9];
  float* out = (float*)d_out;

  char* ws = (char*)d_ws;
  size_t off = 0;
  auto alloc = [&](size_t bytes) { char* p = ws + off; off += (bytes + 255) & ~(size_t)255; return p; };
  unsigned short* hid_bf = (unsigned short*)alloc((size_t)S_LEN * HIDN * 2);
  unsigned short* WqaT   = (unsigned short*)alloc((size_t)QLORA * HIDN * 2);
  unsigned short* WqbT   = (unsigned short*)alloc((size_t)HQ * QLORA * 2);
  unsigned short* WkvaT  = (unsigned short*)alloc((size_t)LATD * HIDN * 2);
  unsigned short* WkvbT  = (unsigned short*)alloc((size_t)HKV * KVLORA * 2);
  unsigned short* WoT    = (unsigned short*)alloc((size_t)HIDN * HO * 2);
  float* q_a    = (float*)alloc((size_t)S_LEN * QLORA * 4);
  unsigned short* qan   = (unsigned short*)alloc((size_t)S_LEN * QLORA * 2);
  float* latent = (float*)alloc((size_t)S_LEN * LATD * 4);
  unsigned short* kvn   = (unsigned short*)alloc((size_t)S_LEN * KVLORA * 2);
  unsigned short* qbuf  = (unsigned short*)alloc((size_t)S_LEN * HQ * 2);
  unsigned short* kvbuf = (unsigned short*)alloc((size_t)S_LEN * HKV * 2);
  unsigned short* kpe   = (unsigned short*)alloc((size_t)S_LEN * DROPE * 2);
  float* ct     = (float*)alloc((size_t)S_LEN * 32 * 4);
  float* st     = (float*)alloc((size_t)S_LEN * 32 * 4);
  unsigned short* attnb = (unsigned short*)alloc((size_t)S_LEN * HO * 2);
  (void)ws_size; (void)in_sizes; (void)n_in; (void)out_size;

  // 0) casts / transposes / tables
  cast_bf16<<<(S_LEN * HIDN / 8 + 255) / 256, 256, 0, stream>>>(hidden, hid_bf, S_LEN * HIDN / 8);
  transpose_cast<<<dim3(QLORA / 64, HIDN / 64), 256, 0, stream>>>(Wq_a, WqaT, HIDN, QLORA);
  transpose_cast<<<dim3(HQ / 64, QLORA / 64), 256, 0, stream>>>(Wq_b, WqbT, QLORA, HQ);
  transpose_cast<<<dim3(LATD / 64, HIDN / 64), 256, 0, stream>>>(Wkv_a, WkvaT, HIDN, LATD);
  transpose_cast<<<dim3(HKV / 64, KVLORA / 64), 256, 0, stream>>>(Wkv_b, WkvbT, KVLORA, HKV);
  transpose_cast<<<dim3(HO / 64, HIDN / 64), 256, 0, stream>>>(Wo, WoT, HIDN, HO);
  rope_tables<<<(S_LEN * 32) / 256, 256, 0, stream>>>(ct, st);

  // 1) projections
  gemm_bf16<false><<<dim3(QLORA / 128, S_LEN / 128), 256, 0, stream>>>(hid_bf, WqaT, q_a, QLORA, HIDN, HIDN, QLORA);
  gemm_bf16<false><<<dim3((LATD + 127) / 128, S_LEN / 128), 256, 0, stream>>>(hid_bf, WkvaT, latent, LATD, HIDN, HIDN, LATD);
  // 2) RMS norms -> bf16
  rmsnorm_cast<<<S_LEN, 256, 0, stream>>>(q_a, q_a_ln, qan, QLORA, QLORA);
  rmsnorm_cast<<<S_LEN, 256, 0, stream>>>(latent, kv_a_ln, kvn, KVLORA, LATD);
  // 3) up-projections
  gemm_bf16<true><<<dim3(HQ / 128, S_LEN / 128), 256, 0, stream>>>(qan, WqbT, qbuf, HQ, QLORA, QLORA, HQ);
  gemm_bf16<true><<<dim3(HKV / 128, S_LEN / 128), 256, 0, stream>>>(kvn, WkvbT, kvbuf, HKV, KVLORA, KVLORA, HKV);
  // 4) RoPE
  rope_apply<<<S_LEN, 256, 0, stream>>>(qbuf, latent, kpe, ct, st, pid);
  // 5) MFMA flash attention (1D grid, balanced pairing)
  attn_mfma<<<dim3(512), 256, 0, stream>>>(qbuf, kvbuf, kpe, mask, attnb);
  // 6) out = attnb @ Wo
  gemm_bf16<false><<<dim3(HO / 128, S_LEN / 128), 256, 0, stream>>>(attnb, WoT, out, HO, HIDN, HIDN, HO);
}

// Round 6
// 635.687 us; speedup vs baseline: 4.1117x; 1.3367x over previous
//
#include <hip/hip_runtime.h>

#define S_LEN 2048
#define HIDN 4096
#define NH 32
#define DQK 192
#define DROPE 64
#define DV 128
#define QLORA 1536
#define KVLORA 512
#define LATD 576      // KVLORA + ROPE
#define NFUSE 2112    // QLORA + LATD
#define HQ 6144       // NH*DQK
#define HKV 8192      // NH*(128+128)
#define HO 4096       // NH*DV

typedef float f32x4 __attribute__((ext_vector_type(4)));
typedef float f32x16 __attribute__((ext_vector_type(16)));
typedef __bf16 bf16x8 __attribute__((ext_vector_type(8)));
typedef unsigned short u16x8 __attribute__((ext_vector_type(8)));
typedef unsigned short u16x4 __attribute__((ext_vector_type(4)));

__device__ __forceinline__ float bf2f(unsigned short u) {
  union { unsigned int i; float f; } v; v.i = (unsigned int)u << 16; return v.f;
}
__device__ __forceinline__ unsigned short f2bf(float f) {   // RNE, finite inputs
  unsigned int u = __float_as_uint(f);
  return (unsigned short)((u + 0x7fffu + ((u >> 16) & 1u)) >> 16);
}
__device__ __forceinline__ void g2l16(const void* g, void* l) {
  __builtin_amdgcn_global_load_lds((__attribute__((address_space(1))) void*)(void*)g,
                                   (__attribute__((address_space(3))) void*)l, 16, 0, 0);
}

// ---------------- bf16 MFMA GEMM: C[M,N] = A[M,K] @ BT[N,K]^T ----------------
template<bool BF16_OUT>
__global__ __launch_bounds__(256) void gemm_bf16(
    const unsigned short* __restrict__ A,   // bf16 [M,K] row-major
    const unsigned short* __restrict__ BT,  // bf16 [N,K] row-major
    void* __restrict__ C, int N, int K, int lda, int ldc)
{
  __shared__ __align__(16) unsigned short As[128][32];
  __shared__ __align__(16) unsigned short Bs[128][32];
  const int t = threadIdx.x;
  const int brow = blockIdx.y, bcol = blockIdx.x;
  const int wave = t >> 6, lane = t & 63;
  const int wr = wave >> 1, wc = wave & 1;       // 64x64 per wave
  const int lm = lane & 15, lk = lane >> 4;

  f32x4 acc[4][4];
#pragma unroll
  for (int i = 0; i < 4; ++i)
#pragma unroll
    for (int j = 0; j < 4; ++j) acc[i][j] = (f32x4){0.f, 0.f, 0.f, 0.f};

  for (int k0 = 0; k0 < K; k0 += 32) {
#pragma unroll
    for (int i = 0; i < 2; ++i) {                 // A tile: 128x32 bf16 = 8KB
      const int c = t + i * 256;
      const int r = c >> 2, ko = (c & 3) * 8;
      g2l16(A + (size_t)(brow * 128 + r) * lda + k0 + ko,
            (char*)&As[0][0] + i * 4096 + wave * 1024);
    }
#pragma unroll
    for (int i = 0; i < 2; ++i) {                 // B^T tile: 128x32
      const int c = t + i * 256;
      const int r = c >> 2, ko = (c & 3) * 8;
      int n = bcol * 128 + r; if (n > N - 1) n = N - 1;   // tail clamp
      g2l16(BT + (size_t)n * K + k0 + ko,
            (char*)&Bs[0][0] + i * 4096 + wave * 1024);
    }
    __syncthreads();
    bf16x8 af[4], bfv[4];
#pragma unroll
    for (int fm = 0; fm < 4; ++fm) af[fm] = *(const bf16x8*)&As[wr * 64 + fm * 16 + lm][lk * 8];
#pragma unroll
    for (int fn = 0; fn < 4; ++fn) bfv[fn] = *(const bf16x8*)&Bs[wc * 64 + fn * 16 + lm][lk * 8];
#pragma unroll
    for (int fm = 0; fm < 4; ++fm)
#pragma unroll
      for (int fn = 0; fn < 4; ++fn)
        acc[fm][fn] = __builtin_amdgcn_mfma_f32_16x16x32_bf16(af[fm], bfv[fn], acc[fm][fn], 0, 0, 0);
    __syncthreads();
  }

#pragma unroll
  for (int fm = 0; fm < 4; ++fm) {
    const int row = brow * 128 + wr * 64 + fm * 16 + lk * 4;
#pragma unroll
    for (int fn = 0; fn < 4; ++fn) {
      const int col = bcol * 128 + wc * 64 + fn * 16 + lm;
      if (col < N) {
#pragma unroll
        for (int r = 0; r < 4; ++r) {
          const float v = acc[fm][fn][r];
          if (BF16_OUT) ((unsigned short*)C)[(size_t)(row + r) * ldc + col] = f2bf(v);
          else          ((float*)C)[(size_t)(row + r) * ldc + col] = v;
        }
      }
    }
  }
}

// ---------------- weight transpose + cast ----------------
__global__ __launch_bounds__(256) void transpose_cast(
    const float* __restrict__ W, unsigned short* __restrict__ WT, int K, int N)
{
  __shared__ float tl[64][65];
  const int n0 = blockIdx.x * 64, k0 = blockIdx.y * 64;
  const int t = threadIdx.x;
  const int c = t & 63, rb = t >> 6;
#pragma unroll
  for (int i = 0; i < 16; ++i) {
    const int r = i * 4 + rb;
    tl[r][c] = W[(size_t)(k0 + r) * N + n0 + c];
  }
  __syncthreads();
#pragma unroll
  for (int i = 0; i < 16; ++i) {
    const int r = i * 4 + rb;
    WT[(size_t)(n0 + r) * K + k0 + c] = f2bf(tl[c][r]);
  }
}

// ---------------- elementwise fp32 -> bf16 ----------------
__global__ __launch_bounds__(256) void cast_bf16(
    const float* __restrict__ x, unsigned short* __restrict__ y, int n8)
{
  const int i = blockIdx.x * 256 + threadIdx.x;
  if (i >= n8) return;
  const float4 a = ((const float4*)x)[i * 2];
  const float4 b = ((const float4*)x)[i * 2 + 1];
  u16x8 o;
  o[0] = f2bf(a.x); o[1] = f2bf(a.y); o[2] = f2bf(a.z); o[3] = f2bf(a.w);
  o[4] = f2bf(b.x); o[5] = f2bf(b.y); o[6] = f2bf(b.z); o[7] = f2bf(b.w);
  ((u16x8*)y)[i] = o;
}

// ---------------- RMSNorm fp32 row -> bf16 row ----------------
__global__ __launch_bounds__(256) void rmsnorm_cast(
    const float* __restrict__ x, const float* __restrict__ w,
    unsigned short* __restrict__ y, int N, int ld)
{
  const int r = blockIdx.x;
  const float* row = x + (size_t)r * ld;
  const int t = threadIdx.x;
  const int nf4 = N >> 2;
  float4 v[2]; int cnt = 0; float ss = 0.f;
  for (int i = t; i < nf4; i += 256) {
    float4 vv = ((const float4*)row)[i];
    v[cnt++] = vv;
    ss += vv.x * vv.x + vv.y * vv.y + vv.z * vv.z + vv.w * vv.w;
  }
#pragma unroll
  for (int off = 32; off; off >>= 1) ss += __shfl_xor(ss, off, 64);
  __shared__ float red[4];
  if ((t & 63) == 0) red[t >> 6] = ss;
  __syncthreads();
  ss = red[0] + red[1] + red[2] + red[3];
  const float rn = rsqrtf(ss / (float)N + 1e-6f);
  unsigned short* yrow = y + (size_t)r * N;
  cnt = 0;
  for (int i = t; i < nf4; i += 256) {
    float4 vv = v[cnt++];
    float4 wv = ((const float4*)w)[i];
    ushort4 o = make_ushort4(f2bf(vv.x * rn * wv.x), f2bf(vv.y * rn * wv.y),
                             f2bf(vv.z * rn * wv.z), f2bf(vv.w * rn * wv.w));
    ((ushort4*)yrow)[i] = o;
  }
}

// ---------------- RoPE tables (double-precision inv_freq) ----------------
__global__ __launch_bounds__(256) void rope_tables(float* __restrict__ ct, float* __restrict__ st)
{
  const int idx = blockIdx.x * 256 + threadIdx.x;   // S_LEN*32
  const int s = idx >> 5, j = idx & 31;
  const double inv = exp(-((double)(2 * j) / 64.0) * log(25600000.0));
  const float freq = (float)s * (float)inv;
  ct[idx] = cosf(freq);
  st[idx] = sinf(freq);
}

// ---------------- RoPE apply: q_pe (bf16 in place), k_pe -> bf16 kpe ----------------
// latent points at col 1536 of the fused [S][2112] f32 buffer (stride NFUSE).
__global__ __launch_bounds__(256) void rope_apply(
    unsigned short* __restrict__ q, const float* __restrict__ latent, unsigned short* __restrict__ kpe,
    const float* __restrict__ ct, const float* __restrict__ st, const int* __restrict__ pid)
{
  const int s = blockIdx.x;
  __shared__ float qs[2048];          // 32 heads x 64 rope dims
  const int t = threadIdx.x;
#pragma unroll
  for (int i = 0; i < 8; ++i) {
    const int idx = t + i * 256;
    const int hh = idx >> 6, d = idx & 63;
    qs[idx] = bf2f(q[(size_t)s * HQ + hh * DQK + 128 + d]);
  }
  __syncthreads();
  const int pos = pid[s];
#pragma unroll
  for (int i = 0; i < 4; ++i) {
    const int wi = t + i * 256;       // 32 heads x 32 pairs
    const int hh = wi >> 5, j = wi & 31;
    const float c = ct[pos * 32 + j], sn = st[pos * 32 + j];
    const float x0 = qs[hh * 64 + 2 * j], x1 = qs[hh * 64 + 2 * j + 1];
    q[(size_t)s * HQ + hh * DQK + 128 + j]      = f2bf(x0 * c - x1 * sn);
    q[(size_t)s * HQ + hh * DQK + 128 + 32 + j] = f2bf(x1 * c + x0 * sn);
  }
  if (t < 32) {
    const int j = t;
    const float c = ct[pos * 32 + j], sn = st[pos * 32 + j];
    const float x0 = latent[(size_t)s * NFUSE + 512 + 2 * j];
    const float x1 = latent[(size_t)s * NFUSE + 512 + 2 * j + 1];
    kpe[(size_t)s * DROPE + j]      = f2bf(x0 * c - x1 * sn);
    kpe[(size_t)s * DROPE + 32 + j] = f2bf(x1 * c + x0 * sn);
  }
}

// ---------------- MFMA flash attention v3 ----------------
// 256 equal-work blocks (32 h x 8 pairs); each block: tile qb=15-pr then qb=pr
// (34 chunks total). 8 waves (512 thr) = 4 q-groups x 2 kv-halves -> 2 waves/SIMD.
// Cross-wave softmax max-exchange per chunk; acc merge at tile epilogue.
// Analytic causal mask (no mask tensor reads).
// LDS: Kt[64][192]swz 24K + Vt[128][64]swz 16K + P[4][32][64]swz 16K + xch 1K
#define KT_OFF 0
#define VT_OFF 24576
#define P_OFF  40960
#define XCH_OFF 57344

__global__ __launch_bounds__(512, 2) void attn_mfma(
    const unsigned short* __restrict__ q,      // bf16 [S][HQ]
    const unsigned short* __restrict__ kv,     // bf16 [S][HKV]
    const unsigned short* __restrict__ kpe,    // bf16 [S][64]
    unsigned short* __restrict__ attnb)        // bf16 [S][HO]
{
  __shared__ __align__(16) char lds[58368];
  const int bid = blockIdx.x;                  // 256 blocks
  const int h = bid & 31, pr = bid >> 5;       // pr 0..7
  const int t = threadIdx.x;
  const int wave = t >> 6, lane = t & 63;
  const int qgrp = wave & 3, kvh = wave >> 2;  // q-group, kv-half
  const int lq = lane & 31, lh = lane >> 5;
  const float scale = 0.07216878364870322f;    // 192^-0.5
  float* xchf = (float*)(lds + XCH_OFF);

  // K staging descriptors (pre-swizzled source; 3 16B slots/thread)
  int koff[3], kisk[3];
#pragma unroll
  for (int i = 0; i < 3; ++i) {
    const int s = i * 512 + t;                 // 1536 slots
    const int row = s / 24, csp = s - row * 24;
    const int cs = (csp & ~7) | ((csp & 7) ^ (row & 7));
    if (cs < 16) { koff[i] = row * (HKV * 2) + h * 512 + cs * 16; kisk[i] = 0; }
    else         { koff[i] = row * 128 + (cs - 16) * 16;          kisk[i] = 1; }
  }
  const int vr0 = (t & 31) * 2;                // 2 kv rows
  const int vd0 = (t >> 5) * 8;                // 8 dv cols
  u16x8 vreg[2];

#define STAGE_K(KN) do {                                                        \
    const char* kvc = (const char*)kv + ((size_t)(KN) * 64) * (HKV * 2);        \
    const char* kpc = (const char*)kpe + (size_t)(KN) * 64 * 128;               \
    _Pragma("unroll")                                                           \
    for (int i = 0; i < 3; ++i) {                                               \
      const char* src = kisk[i] ? (kpc + koff[i]) : (kvc + koff[i]);            \
      g2l16(src, (char*)lds + KT_OFF + i * 8192 + wave * 1024);                 \
    }                                                                           \
  } while (0)

#define LOAD_V(KN) do {                                                         \
    vreg[0] = *(const u16x8*)&kv[(size_t)((KN) * 64 + vr0) * HKV + h * 256 + 128 + vd0];     \
    vreg[1] = *(const u16x8*)&kv[(size_t)((KN) * 64 + vr0 + 1) * HKV + h * 256 + 128 + vd0]; \
  } while (0)

#define WRITE_V() do {                                                          \
    _Pragma("unroll")                                                           \
    for (int j = 0; j < 8; ++j) {                                               \
      const int dv = vd0 + j;                                                   \
      const unsigned int pk = (unsigned int)(unsigned short)vreg[0][j] |        \
                              ((unsigned int)(unsigned short)vreg[1][j] << 16); \
      *(unsigned int*)&lds[VT_OFF + ((dv * 128 + vr0 * 2) ^ ((dv & 7) << 4))] = pk; \
    }                                                                           \
  } while (0)

  for (int ph = 0; ph < 2; ++ph) {
    const int qb = ph ? pr : 15 - pr;          // heavy tile first
    const int Q0 = qb * 128;
    const int gq = Q0 + qgrp * 32 + lq;
    const int nc = 2 * qb + 2;

    bf16x8 qf[12];
#pragma unroll
    for (int f = 0; f < 12; ++f)
      qf[f] = *(const bf16x8*)&q[(size_t)gq * HQ + h * DQK + f * 16 + lh * 8];

    f32x16 acc0, acc1, acc2, acc3;
#pragma unroll
    for (int i = 0; i < 16; ++i) { acc0[i] = 0.f; acc1[i] = 0.f; acc2[i] = 0.f; acc3[i] = 0.f; }
    float m = -INFINITY, l = 0.f;

    __syncthreads();                           // prior phase's LDS reads done
    STAGE_K(0);
    LOAD_V(0);
    __syncthreads();                           // vmcnt drained
    WRITE_V();
    __syncthreads();

    for (int c = 0; c < nc; ++c) {
      const int k0 = c * 64;
      const bool last = (c == nc - 1);
      if (!last) LOAD_V(c + 1);                // in flight until barrier B

      // ---- QK half: S = K[kv-half] . Q^T (12 mfma) ----
      f32x16 s;
#pragma unroll
      for (int i = 0; i < 16; ++i) s[i] = 0.f;
      const int sw0 = (lq & 7) << 4;
      const int krow = kvh * 32 + lq;
      __builtin_amdgcn_s_setprio(1);
#pragma unroll
      for (int kf = 0; kf < 12; ++kf) {
        bf16x8 a = *(const bf16x8*)&lds[KT_OFF + ((krow * 384 + kf * 32 + lh * 16) ^ sw0)];
        s = __builtin_amdgcn_mfma_f32_32x32x16_bf16(a, qf[kf], s, 0, 0, 0);
      }
      __builtin_amdgcn_s_setprio(0);

      // ---- analytic causal mask + scale ----
      float x[16];
      if (c >= nc - 2) {
#pragma unroll
        for (int r = 0; r < 16; ++r) {
          const int gkv = k0 + kvh * 32 + (r & 3) + 8 * (r >> 2) + 4 * lh;
          x[r] = (gkv <= gq) ? s[r] * scale : -1e9f;
        }
      } else {
#pragma unroll
        for (int r = 0; r < 16; ++r) x[r] = s[r] * scale;
      }

      // ---- cross-wave online softmax ----
      float hm = x[0];
#pragma unroll
      for (int r = 1; r < 16; ++r) hm = fmaxf(hm, x[r]);
      hm = fmaxf(hm, __shfl_xor(hm, 32, 64));
      xchf[kvh * 128 + qgrp * 32 + lq] = hm;
      __syncthreads();                         // A: Kt reads done + hm published
      if (!last) STAGE_K(c + 1);               // async DMA under softmax+PV
      const float cm = fmaxf(hm, xchf[(1 - kvh) * 128 + qgrp * 32 + lq]);

      if (!__all(cm <= m + 8.0f)) {            // defer-rescale (THR=8)
        const float mn = fmaxf(m, cm);
        const float alpha = __expf(m - mn);
        m = mn; l *= alpha;
#pragma unroll
        for (int r = 0; r < 16; ++r) {
          const int qrow = (r & 3) + 8 * (r >> 2) + 4 * lh;
          const float af = __shfl(alpha, qrow, 32);
          acc0[r] *= af; acc1[r] *= af; acc2[r] *= af; acc3[r] *= af;
        }
      }
      float ps = 0.f;
#pragma unroll
      for (int r = 0; r < 16; ++r) { x[r] = __expf(x[r] - m); ps += x[r]; }
      ps += __shfl_xor(ps, 32, 64);
      l += ps;                                 // per-half l; merged at epilogue

      // ---- P[own 32-kv half] -> LDS bf16 ----
      char* pb = &lds[P_OFF + qgrp * 4096];
#pragma unroll
      for (int rq = 0; rq < 4; ++rq) {
        u16x4 pk;
        pk[0] = f2bf(x[4 * rq + 0]); pk[1] = f2bf(x[4 * rq + 1]);
        pk[2] = f2bf(x[4 * rq + 2]); pk[3] = f2bf(x[4 * rq + 3]);
        *(u16x4*)&pb[(lq * 128 + kvh * 64 + 16 * rq + 8 * lh) ^ sw0] = pk;
      }

      // ---- PV half: acc += P[:,half] @ V[half]^T (8 mfma) ----
      __builtin_amdgcn_s_setprio(1);
#pragma unroll
      for (int kf = 0; kf < 2; ++kf) {
        bf16x8 pa = *(const bf16x8*)&pb[(lq * 128 + kvh * 64 + kf * 32 + lh * 16) ^ sw0];
        bf16x8 v0 = *(const bf16x8*)&lds[VT_OFF + (((0 * 32 + lq) * 128 + kvh * 64 + kf * 32 + lh * 16) ^ sw0)];
        bf16x8 v1 = *(const bf16x8*)&lds[VT_OFF + (((1 * 32 + lq) * 128 + kvh * 64 + kf * 32 + lh * 16) ^ sw0)];
        bf16x8 v2 = *(const bf16x8*)&lds[VT_OFF + (((2 * 32 + lq) * 128 + kvh * 64 + kf * 32 + lh * 16) ^ sw0)];
        bf16x8 v3 = *(const bf16x8*)&lds[VT_OFF + (((3 * 32 + lq) * 128 + kvh * 64 + kf * 32 + lh * 16) ^ sw0)];
        acc0 = __builtin_amdgcn_mfma_f32_32x32x16_bf16(pa, v0, acc0, 0, 0, 0);
        acc1 = __builtin_amdgcn_mfma_f32_32x32x16_bf16(pa, v1, acc1, 0, 0, 0);
        acc2 = __builtin_amdgcn_mfma_f32_32x32x16_bf16(pa, v2, acc2, 0, 0, 0);
        acc3 = __builtin_amdgcn_mfma_f32_32x32x16_bf16(pa, v3, acc3, 0, 0, 0);
      }
      __builtin_amdgcn_s_setprio(0);

      if (!last) {
        __syncthreads();                       // B: Vt reads done; vmcnt(0) drains DMA+V
        WRITE_V();
        __syncthreads();                       // C: chunk c+1 fully staged
      }
    }

    // ---- epilogue: merge kv-halves (scratch overlays Kt/Vt), write output ----
    __syncthreads();
    if (kvh == 1) xchf[qgrp * 32 + lq] = l;
    char* scr = (char*)lds;
    const int sb = qgrp * 8192 + (lh * 32 + lq) * 128;
    const int sws = (lq & 7) << 4;
    if (kvh == 1) {
#pragma unroll
      for (int i = 0; i < 4; ++i) {
        f32x4 a = {acc0[4 * i], acc0[4 * i + 1], acc0[4 * i + 2], acc0[4 * i + 3]};
        f32x4 b = {acc1[4 * i], acc1[4 * i + 1], acc1[4 * i + 2], acc1[4 * i + 3]};
        *(f32x4*)&scr[sb + ((i * 16) ^ sws)] = a;
        *(f32x4*)&scr[sb + ((64 + i * 16) ^ sws)] = b;
      }
    }
    __syncthreads();
    if (kvh == 0) {
#pragma unroll
      for (int i = 0; i < 4; ++i) {
        f32x4 a = *(const f32x4*)&scr[sb + ((i * 16) ^ sws)];
        f32x4 b = *(const f32x4*)&scr[sb + ((64 + i * 16) ^ sws)];
#pragma unroll
        for (int j = 0; j < 4; ++j) { acc0[4 * i + j] += a[j]; acc1[4 * i + j] += b[j]; }
      }
    }
    __syncthreads();
    if (kvh == 1) {
#pragma unroll
      for (int i = 0; i < 4; ++i) {
        f32x4 a = {acc2[4 * i], acc2[4 * i + 1], acc2[4 * i + 2], acc2[4 * i + 3]};
        f32x4 b = {acc3[4 * i], acc3[4 * i + 1], acc3[4 * i + 2], acc3[4 * i + 3]};
        *(f32x4*)&scr[sb + ((i * 16) ^ sws)] = a;
        *(f32x4*)&scr[sb + ((64 + i * 16) ^ sws)] = b;
      }
    }
    __syncthreads();
    if (kvh == 0) {
#pragma unroll
      for (int i = 0; i < 4; ++i) {
        f32x4 a = *(const f32x4*)&scr[sb + ((i * 16) ^ sws)];
        f32x4 b = *(const f32x4*)&scr[sb + ((64 + i * 16) ^ sws)];
#pragma unroll
        for (int j = 0; j < 4; ++j) { acc2[4 * i + j] += a[j]; acc3[4 * i + j] += b[j]; }
      }
      const float ltot = l + xchf[qgrp * 32 + lq];
#pragma unroll
      for (int r = 0; r < 16; ++r) {
        const int qrow = (r & 3) + 8 * (r >> 2) + 4 * lh;
        const float rl = 1.0f / __shfl(ltot, qrow, 32);
        unsigned short* orow = &attnb[(size_t)(Q0 + qgrp * 32 + qrow) * HO + h * DV + lq];
        orow[0]  = f2bf(acc0[r] * rl);
        orow[32] = f2bf(acc1[r] * rl);
        orow[64] = f2bf(acc2[r] * rl);
        orow[96] = f2bf(acc3[r] * rl);
      }
    }
  }
#undef STAGE_K
#undef LOAD_V
#undef WRITE_V
}

// ---------------- launch ----------------
extern "C" void kernel_launch(void* const* d_in, const int* in_sizes, int n_in,
                              void* d_out, int out_size, void* d_ws, size_t ws_size,
                              hipStream_t stream) {
  const float* hidden = (const float*)d_in[0];
  const int*   pid    = (const int*)d_in[2];
  const float* Wq_a   = (const float*)d_in[3];
  const float* q_a_ln = (const float*)d_in[4];
  const float* Wq_b   = (const float*)d_in[5];
  const float* Wkv_a  = (const float*)d_in[6];
  const float* kv_a_ln= (const float*)d_in[7];
  const float* Wkv_b  = (const float*)d_in[8];
  const float* Wo     = (const float*)d_in[9];
  float* out = (float*)d_out;

  char* ws = (char*)d_ws;
  size_t off = 0;
  auto alloc = [&](size_t bytes) { char* p = ws + off; off += (bytes + 255) & ~(size_t)255; return p; };
  unsigned short* hid_bf = (unsigned short*)alloc((size_t)S_LEN * HIDN * 2);
  unsigned short* WcatT  = (unsigned short*)alloc((size_t)NFUSE * HIDN * 2);   // [Wq_a^T ; Wkv_a^T]
  unsigned short* WqbT   = (unsigned short*)alloc((size_t)HQ * QLORA * 2);
  unsigned short* WkvbT  = (unsigned short*)alloc((size_t)HKV * KVLORA * 2);
  unsigned short* WoT    = (unsigned short*)alloc((size_t)HIDN * HO * 2);
  float* qkva   = (float*)alloc((size_t)S_LEN * NFUSE * 4);                    // fused q_a|latent f32
  unsigned short* qan   = (unsigned short*)alloc((size_t)S_LEN * QLORA * 2);
  unsigned short* kvn   = (unsigned short*)alloc((size_t)S_LEN * KVLORA * 2);
  unsigned short* qbuf  = (unsigned short*)alloc((size_t)S_LEN * HQ * 2);
  unsigned short* kvbuf = (unsigned short*)alloc((size_t)S_LEN * HKV * 2);
  unsigned short* kpe   = (unsigned short*)alloc((size_t)S_LEN * DROPE * 2);
  float* ct     = (float*)alloc((size_t)S_LEN * 32 * 4);
  float* st     = (float*)alloc((size_t)S_LEN * 32 * 4);
  unsigned short* attnb = (unsigned short*)alloc((size_t)S_LEN * HO * 2);
  (void)ws_size; (void)in_sizes; (void)n_in; (void)out_size;

  // 0) casts / transposes / tables
  cast_bf16<<<(S_LEN * HIDN / 8 + 255) / 256, 256, 0, stream>>>(hidden, hid_bf, S_LEN * HIDN / 8);
  transpose_cast<<<dim3(QLORA / 64, HIDN / 64), 256, 0, stream>>>(Wq_a, WcatT, HIDN, QLORA);
  transpose_cast<<<dim3(LATD / 64, HIDN / 64), 256, 0, stream>>>(Wkv_a, WcatT + (size_t)QLORA * HIDN, HIDN, LATD);
  transpose_cast<<<dim3(HQ / 64, QLORA / 64), 256, 0, stream>>>(Wq_b, WqbT, QLORA, HQ);
  transpose_cast<<<dim3(HKV / 64, KVLORA / 64), 256, 0, stream>>>(Wkv_b, WkvbT, KVLORA, HKV);
  transpose_cast<<<dim3(HO / 64, HIDN / 64), 256, 0, stream>>>(Wo, WoT, HIDN, HO);
  rope_tables<<<(S_LEN * 32) / 256, 256, 0, stream>>>(ct, st);

  // 1) fused down-projection: [q_a | latent] = hidden @ [Wq_a | Wkv_a]
  gemm_bf16<false><<<dim3((NFUSE + 127) / 128, S_LEN / 128), 256, 0, stream>>>(hid_bf, WcatT, qkva, NFUSE, HIDN, HIDN, NFUSE);
  // 2) RMS norms -> bf16
  rmsnorm_cast<<<S_LEN, 256, 0, stream>>>(qkva, q_a_ln, qan, QLORA, NFUSE);
  rmsnorm_cast<<<S_LEN, 256, 0, stream>>>(qkva + QLORA, kv_a_ln, kvn, KVLORA, NFUSE);
  // 3) up-projections
  gemm_bf16<true><<<dim3(HQ / 128, S_LEN / 128), 256, 0, stream>>>(qan, WqbT, qbuf, HQ, QLORA, QLORA, HQ);
  gemm_bf16<true><<<dim3(HKV / 128, S_LEN / 128), 256, 0, stream>>>(kvn, WkvbT, kvbuf, HKV, KVLORA, KVLORA, HKV);
  // 4) RoPE
  rope_apply<<<S_LEN, 256, 0, stream>>>(qbuf, qkva + QLORA, kpe, ct, st, pid);
  // 5) MFMA flash attention v3 (equal-work blocks)
  attn_mfma<<<dim3(256), 512, 0, stream>>>(qbuf, kvbuf, kpe, attnb);
  // 6) out = attnb @ Wo
  gemm_bf16<false><<<dim3(HO / 128, S_LEN / 128), 256, 0, stream>>>(attnb, WoT, out, HO, HIDN, HIDN, HO);
}